// Round 5
// baseline (245.952 us; speedup 1.0000x reference)
//
#include <hip/hip_runtime.h>
#include <math.h>

typedef unsigned int u32;

static __device__ __forceinline__ float lrelu(float x){ return x > 0.f ? x : 0.01f * x; }

// ---- workspace layout (float offsets) ----
#define OFF_EO    0         // 768*128
#define OFF_EA    98304     // 768*128
#define OFF_XE    196608    // 768*128
#define OFF_XA    294912    // 768*128
#define OFF_QKVE  393216    // 768*384
#define OFF_QKVA  688128    // 768*384
#define OFF_SE    983040    // 4*768*768
#define OFF_AOE   3342336   // 768*128
#define OFF_AOA   3440640   // 15*96*128
#define OFF_QVE   3624960   // 768
#define OFF_QVA   3625728   // 15*96
#define WS_FLOATS 3627168   // ~14.5 MB

// ---- output layout (fp32 elems) ----
#define OUT_POL 0
#define OUT_QV  24576
#define OUT_EO  25344

#define SCALE_ATTN 0.17677669529663689f  // 1/sqrt(32)

// ================================================================
// K1: actor (3 layers + gelu) + obs encoder + obs-act encoder.
// 2 rows (b,n) per block, 256 threads. grid=384.
// ================================================================
__global__ __launch_bounds__(256) void k1_actor_enc(
    const float* __restrict__ obs,
    const float* __restrict__ aw1, const float* __restrict__ ab1,
    const float* __restrict__ aw2, const float* __restrict__ ab2,
    const float* __restrict__ aw3, const float* __restrict__ ab3,
    const float* __restrict__ eow, const float* __restrict__ eob,
    const float* __restrict__ eaw, const float* __restrict__ eab,
    float* __restrict__ out, float* __restrict__ ws)
{
  __shared__ float obs_s[2][128];
  __shared__ float h1[2][256];
  __shared__ float h2[2][128];
  __shared__ float pol[2][32];
  const int t  = threadIdx.x;
  const int r0 = blockIdx.x * 2;

  { int r = t >> 7, k = t & 127;
    obs_s[r][k] = obs[(r0 + r) * 128 + k]; }
  __syncthreads();

  { // layer1: 256 outputs x 2 rows
    const int o = t;
    float a0 = ab1[o]; float a1 = a0;
    const float4* wr = (const float4*)(aw1 + o * 128);
    #pragma unroll 8
    for (int kk = 0; kk < 32; ++kk) {
      float4 w = wr[kk];
      const int k = kk * 4;
      a0 = fmaf(obs_s[0][k], w.x, a0); a0 = fmaf(obs_s[0][k+1], w.y, a0);
      a0 = fmaf(obs_s[0][k+2], w.z, a0); a0 = fmaf(obs_s[0][k+3], w.w, a0);
      a1 = fmaf(obs_s[1][k], w.x, a1); a1 = fmaf(obs_s[1][k+1], w.y, a1);
      a1 = fmaf(obs_s[1][k+2], w.z, a1); a1 = fmaf(obs_s[1][k+3], w.w, a1);
    }
    h1[0][o] = lrelu(a0); h1[1][o] = lrelu(a1);
  }
  __syncthreads();

  if (t < 128) { // layer2: 128 outputs x 2 rows
    const int o = t;
    float a0 = ab2[o]; float a1 = a0;
    const float4* wr = (const float4*)(aw2 + o * 256);
    #pragma unroll 8
    for (int kk = 0; kk < 64; ++kk) {
      float4 w = wr[kk];
      const int k = kk * 4;
      a0 = fmaf(h1[0][k], w.x, a0); a0 = fmaf(h1[0][k+1], w.y, a0);
      a0 = fmaf(h1[0][k+2], w.z, a0); a0 = fmaf(h1[0][k+3], w.w, a0);
      a1 = fmaf(h1[1][k], w.x, a1); a1 = fmaf(h1[1][k+1], w.y, a1);
      a1 = fmaf(h1[1][k+2], w.z, a1); a1 = fmaf(h1[1][k+3], w.w, a1);
    }
    h2[0][o] = lrelu(a0); h2[1][o] = lrelu(a1);
  }
  __syncthreads();

  if (t < 64) { // layer3 + exact GELU -> policy
    const int o = t & 31, r = t >> 5;
    float a = ab3[o];
    const float4* wr = (const float4*)(aw3 + o * 128);
    #pragma unroll 8
    for (int kk = 0; kk < 32; ++kk) {
      float4 w = wr[kk];
      const int k = kk * 4;
      a = fmaf(h2[r][k], w.x, a); a = fmaf(h2[r][k+1], w.y, a);
      a = fmaf(h2[r][k+2], w.z, a); a = fmaf(h2[r][k+3], w.w, a);
    }
    float g = 0.5f * a * (1.f + erff(a * 0.70710678118654752f));
    pol[r][o] = g;
    out[OUT_POL + (r0 + r) * 32 + o] = g;
  }
  __syncthreads();

  if (t < 128) { // eo = obs @ eow^T + eob
    const int o = t;
    float a0 = eob[o]; float a1 = a0;
    const float4* wr = (const float4*)(eow + o * 128);
    #pragma unroll 8
    for (int kk = 0; kk < 32; ++kk) {
      float4 w = wr[kk];
      const int k = kk * 4;
      a0 = fmaf(obs_s[0][k], w.x, a0); a0 = fmaf(obs_s[0][k+1], w.y, a0);
      a0 = fmaf(obs_s[0][k+2], w.z, a0); a0 = fmaf(obs_s[0][k+3], w.w, a0);
      a1 = fmaf(obs_s[1][k], w.x, a1); a1 = fmaf(obs_s[1][k+1], w.y, a1);
      a1 = fmaf(obs_s[1][k+2], w.z, a1); a1 = fmaf(obs_s[1][k+3], w.w, a1);
    }
    ws[OFF_EO + (r0 + 0) * 128 + o] = a0;
    ws[OFF_EO + (r0 + 1) * 128 + o] = a1;
    out[OUT_EO + (r0 + 0) * 128 + o] = a0;
    out[OUT_EO + (r0 + 1) * 128 + o] = a1;
  } else {       // ea = [obs, policy] @ eaw^T + eab
    const int o = t - 128;
    float a0 = eab[o]; float a1 = a0;
    const float4* wr = (const float4*)(eaw + o * 160);  // 40 float4
    #pragma unroll 8
    for (int kk = 0; kk < 32; ++kk) {
      float4 w = wr[kk];
      const int k = kk * 4;
      a0 = fmaf(obs_s[0][k], w.x, a0); a0 = fmaf(obs_s[0][k+1], w.y, a0);
      a0 = fmaf(obs_s[0][k+2], w.z, a0); a0 = fmaf(obs_s[0][k+3], w.w, a0);
      a1 = fmaf(obs_s[1][k], w.x, a1); a1 = fmaf(obs_s[1][k+1], w.y, a1);
      a1 = fmaf(obs_s[1][k+2], w.z, a1); a1 = fmaf(obs_s[1][k+3], w.w, a1);
    }
    #pragma unroll
    for (int kk = 32; kk < 40; ++kk) {
      float4 w = wr[kk];
      const int k = kk * 4 - 128;
      a0 = fmaf(pol[0][k], w.x, a0); a0 = fmaf(pol[0][k+1], w.y, a0);
      a0 = fmaf(pol[0][k+2], w.z, a0); a0 = fmaf(pol[0][k+3], w.w, a0);
      a1 = fmaf(pol[1][k], w.x, a1); a1 = fmaf(pol[1][k+1], w.y, a1);
      a1 = fmaf(pol[1][k+2], w.z, a1); a1 = fmaf(pol[1][k+3], w.w, a1);
    }
    ws[OFF_EA + (r0 + 0) * 128 + o] = a0;
    ws[OFF_EA + (r0 + 1) * 128 + o] = a1;
  }
}

// ================================================================
// K2: x = relu(riw@in + rib); qkv = miw@x + mib. grid=384.
// NOTE: 768 is NOT pow2 -> use subtraction, not &767 (round-4 bug).
// ================================================================
__global__ __launch_bounds__(256) void k2_rsa_in(
    const float* __restrict__ riw, const float* __restrict__ rib,
    const float* __restrict__ miw, const float* __restrict__ mib,
    float* __restrict__ ws)
{
  __shared__ float xin[4][128];
  __shared__ float xx[4][128];
  const int t  = threadIdx.x;
  const int R0 = blockIdx.x * 4;
  const int which = (R0 >= 768);
  const int r    = which ? (R0 - 768) : R0;   // FIX: was R0 & 767
  const float* inb = ws + (which ? OFF_EA : OFF_EO) + r * 128;
  float* xout = ws + (which ? OFF_XA : OFF_XE) + r * 128;
  float* qout = ws + (which ? OFF_QKVA : OFF_QKVE) + (size_t)r * 384;

  for (int f = t; f < 512; f += 256) xin[f >> 7][f & 127] = inb[f];
  __syncthreads();

  { // x phase
    const int o = t & 127, p = (t >> 7) * 2;
    float a0 = rib[o]; float a1 = a0;
    const float4* wr = (const float4*)(riw + o * 128);
    #pragma unroll 8
    for (int kk = 0; kk < 32; ++kk) {
      float4 w = wr[kk];
      const int k = kk * 4;
      a0 = fmaf(xin[p][k], w.x, a0); a0 = fmaf(xin[p][k+1], w.y, a0);
      a0 = fmaf(xin[p][k+2], w.z, a0); a0 = fmaf(xin[p][k+3], w.w, a0);
      a1 = fmaf(xin[p+1][k], w.x, a1); a1 = fmaf(xin[p+1][k+1], w.y, a1);
      a1 = fmaf(xin[p+1][k+2], w.z, a1); a1 = fmaf(xin[p+1][k+3], w.w, a1);
    }
    a0 = fmaxf(a0, 0.f); a1 = fmaxf(a1, 0.f);
    xx[p][o] = a0; xx[p + 1][o] = a1;
    xout[p * 128 + o] = a0; xout[(p + 1) * 128 + o] = a1;
  }
  __syncthreads();

  #pragma unroll
  for (int p3 = 0; p3 < 3; ++p3) {
    const int o = p3 * 128 + (t & 127), p = (t >> 7) * 2;
    float a0 = mib[o]; float a1 = a0;
    const float4* wr = (const float4*)(miw + o * 128);
    #pragma unroll 8
    for (int kk = 0; kk < 32; ++kk) {
      float4 w = wr[kk];
      const int k = kk * 4;
      a0 = fmaf(xx[p][k], w.x, a0); a0 = fmaf(xx[p][k+1], w.y, a0);
      a0 = fmaf(xx[p][k+2], w.z, a0); a0 = fmaf(xx[p][k+3], w.w, a0);
      a1 = fmaf(xx[p+1][k], w.x, a1); a1 = fmaf(xx[p+1][k+1], w.y, a1);
      a1 = fmaf(xx[p+1][k+2], w.z, a1); a1 = fmaf(xx[p+1][k+3], w.w, a1);
    }
    qout[(size_t)p * 384 + o] = a0;
    qout[(size_t)(p + 1) * 384 + o] = a1;
  }
}

// ================================================================
// K3: slice j=0 scores. 64x64 tile, grid (12 m, 12 l, 4 heads).
// ================================================================
__global__ __launch_bounds__(256) void k3_scores_e(float* __restrict__ ws)
{
  __shared__ float Qt[64 * 33];
  __shared__ float Kt[64 * 33];
  const int t  = threadIdx.x;
  const int m0 = blockIdx.x * 64, l0 = blockIdx.y * 64, h = blockIdx.z;
  const float* qkve = ws + OFF_QKVE;

  for (int f = t; f < 2048; f += 256) {
    int i = f >> 5, d = f & 31;
    Qt[i * 33 + d] = qkve[(size_t)(l0 + i) * 384 + h * 32 + d];
    Kt[i * 33 + d] = qkve[(size_t)(m0 + i) * 384 + 128 + h * 32 + d];
  }
  __syncthreads();

  const int lq = (t >> 4) * 4, mq = (t & 15) * 4;
  float acc[4][4] = {{0.f}};
  #pragma unroll
  for (int d = 0; d < 32; ++d) {
    float q[4], k[4];
    #pragma unroll
    for (int r = 0; r < 4; ++r) q[r] = Qt[(lq + r) * 33 + d];
    #pragma unroll
    for (int c = 0; c < 4; ++c) k[c] = Kt[(mq + c) * 33 + d];
    #pragma unroll
    for (int r = 0; r < 4; ++r)
      #pragma unroll
      for (int c = 0; c < 4; ++c) acc[r][c] = fmaf(q[r], k[c], acc[r][c]);
  }
  float* Se = ws + OFF_SE;
  #pragma unroll
  for (int r = 0; r < 4; ++r) {
    float4 v;
    v.x = acc[r][0] * SCALE_ATTN; v.y = acc[r][1] * SCALE_ATTN;
    v.z = acc[r][2] * SCALE_ATTN; v.w = acc[r][3] * SCALE_ATTN;
    *(float4*)(Se + ((size_t)h * 768 + l0 + lq + r) * 768 + m0 + mq) = v;
  }
}

// ================================================================
// K5: slice j=0 fused softmax + P@V. grid (48, 4).
// ================================================================
__global__ __launch_bounds__(256) void k5_softmax_av_e(float* __restrict__ ws)
{
  __shared__ __align__(16) float Pt[16 * 68];
  __shared__ float Vt[64 * 33];
  __shared__ float red[16][17];
  __shared__ float rmax[16], rinv[16];
  const int t  = threadIdx.x;
  const int l0 = blockIdx.x * 16, h = blockIdx.y;
  const float* Se   = ws + OFF_SE + (size_t)h * 768 * 768;
  const float* qkve = ws + OFF_QKVE;

  const int li = t >> 4, ln = t & 15;
  const float* srow = Se + (size_t)(l0 + li) * 768;

  float mx = -1e30f;
  for (int m = ln; m < 768; m += 16) mx = fmaxf(mx, srow[m]);
  red[li][ln] = mx;
  __syncthreads();
  if (t < 16) { float m2 = red[t][0];
    #pragma unroll
    for (int i = 1; i < 16; ++i) m2 = fmaxf(m2, red[t][i]);
    rmax[t] = m2; }
  __syncthreads();
  const float rm = rmax[li];
  float sm = 0.f;
  for (int m = ln; m < 768; m += 16) sm += expf(srow[m] - rm);
  red[li][ln] = sm;
  __syncthreads();
  if (t < 16) { float s2 = 0.f;
    #pragma unroll
    for (int i = 0; i < 16; ++i) s2 += red[t][i];
    rinv[t] = 1.f / s2; }
  __syncthreads();

  const int ro = t >> 5, d = t & 31;
  float acc0 = 0.f, acc1 = 0.f;
  for (int mt = 0; mt < 12; ++mt) {
    const int m0 = mt * 64;
    for (int f = t; f < 1024; f += 256) {
      int i = f >> 6, mm = f & 63;
      float s = Se[(size_t)(l0 + i) * 768 + m0 + mm];
      Pt[i * 68 + mm] = expf(s - rmax[i]) * rinv[i];
    }
    for (int f = t; f < 2048; f += 256) {
      int i = f >> 5, dd = f & 31;
      Vt[i * 33 + dd] = qkve[(size_t)(m0 + i) * 384 + 256 + h * 32 + dd];
    }
    __syncthreads();
    #pragma unroll
    for (int m4 = 0; m4 < 16; ++m4) {
      float4 p0 = *(const float4*)&Pt[ro * 68 + m4 * 4];
      float4 p1 = *(const float4*)&Pt[(ro + 8) * 68 + m4 * 4];
      float v0 = Vt[(m4 * 4 + 0) * 33 + d];
      float v1 = Vt[(m4 * 4 + 1) * 33 + d];
      float v2 = Vt[(m4 * 4 + 2) * 33 + d];
      float v3 = Vt[(m4 * 4 + 3) * 33 + d];
      acc0 = fmaf(p0.x, v0, fmaf(p0.y, v1, fmaf(p0.z, v2, fmaf(p0.w, v3, acc0))));
      acc1 = fmaf(p1.x, v0, fmaf(p1.y, v1, fmaf(p1.z, v2, fmaf(p1.w, v3, acc1))));
    }
    __syncthreads();
  }
  float* aoe = ws + OFF_AOE;
  aoe[(size_t)(l0 + ro) * 128 + h * 32 + d]     = acc0;
  aoe[(size_t)(l0 + ro + 8) * 128 + h * 32 + d] = acc1;
}

// ================================================================
// K6: slices j=1..15, dedup'd weighted softmax. grid=120.
// ================================================================
__global__ __launch_bounds__(256) void k6_a_slices(float* __restrict__ ws)
{
  __shared__ float Qb[48 * 33];
  __shared__ float Ka[96 * 33];
  __shared__ __align__(16) float Va[96 * 36];
  __shared__ float Ss[48 * 97];
  __shared__ float rinv[48];
  const int t  = threadIdx.x;
  const int z  = blockIdx.x;
  const int j1 = z >> 3;            // 0..14
  const int h  = (z & 7) >> 1, rb = z & 1;
  const int jj = j1 + 1;            // slice 1..15
  const float* qkva = ws + OFF_QKVA;

  for (int f = t; f < 3072; f += 256) {
    int ml = f >> 5, d = f & 31;
    int bp = ml >> 1, sp = ml & 1;
    int ag = sp ? jj : (jj - 1);
    const float* src = qkva + (size_t)(bp * 16 + ag) * 384 + h * 32 + d;
    Ka[ml * 33 + d] = src[128];
    Va[ml * 36 + d] = src[256];
  }
  for (int f = t; f < 1536; f += 256) {
    int ql = f >> 5, d = f & 31;
    int Lb = rb * 48 + ql;
    int b = Lb >> 1, s = Lb & 1;
    int ag = s ? jj : (jj - 1);
    Qb[ql * 33 + d] = qkva[(size_t)(b * 16 + ag) * 384 + h * 32 + d];
  }
  __syncthreads();

  { // scores 48x96
    const int tl = (t >> 4) * 3, tm = (t & 15) * 6;
    float acc[3][6] = {{0.f}};
    #pragma unroll
    for (int d = 0; d < 32; ++d) {
      float q[3], k[6];
      #pragma unroll
      for (int r = 0; r < 3; ++r) q[r] = Qb[(tl + r) * 33 + d];
      #pragma unroll
      for (int c = 0; c < 6; ++c) k[c] = Ka[(tm + c) * 33 + d];
      #pragma unroll
      for (int r = 0; r < 3; ++r)
        #pragma unroll
        for (int c = 0; c < 6; ++c) acc[r][c] = fmaf(q[r], k[c], acc[r][c]);
    }
    #pragma unroll
    for (int r = 0; r < 3; ++r)
      #pragma unroll
      for (int c = 0; c < 6; ++c) Ss[(tl + r) * 97 + tm + c] = acc[r][c] * SCALE_ATTN;
  }
  __syncthreads();

  if (t < 48) { // weighted softmax per row
    float* rowp = Ss + t * 97;
    float mx = rowp[0];
    for (int m = 1; m < 96; ++m) mx = fmaxf(mx, rowp[m]);
    const float wj = (float)jj, wnj = (float)(16 - jj);
    float sum = 0.f;
    for (int m = 0; m < 96; ++m) {
      float w = (m & 1) ? wj : wnj;
      float p = w * expf(rowp[m] - mx);
      rowp[m] = p; sum += p;
    }
    rinv[t] = 1.f / sum;
  }
  __syncthreads();

  if (t < 192) { // P@V
    const int l0 = (t >> 3) * 2, d0 = (t & 7) * 4;
    float a0x=0.f,a0y=0.f,a0z=0.f,a0w=0.f, a1x=0.f,a1y=0.f,a1z=0.f,a1w=0.f;
    for (int m = 0; m < 96; ++m) {
      float p0 = Ss[l0 * 97 + m], p1 = Ss[(l0 + 1) * 97 + m];
      float4 v = *(const float4*)&Va[m * 36 + d0];
      a0x = fmaf(p0, v.x, a0x); a0y = fmaf(p0, v.y, a0y);
      a0z = fmaf(p0, v.z, a0z); a0w = fmaf(p0, v.w, a0w);
      a1x = fmaf(p1, v.x, a1x); a1y = fmaf(p1, v.y, a1y);
      a1z = fmaf(p1, v.z, a1z); a1w = fmaf(p1, v.w, a1w);
    }
    const float s0 = rinv[l0], s1 = rinv[l0 + 1];
    float* ao = ws + OFF_AOA + (size_t)(j1 * 96 + rb * 48 + l0) * 128 + h * 32 + d0;
    float4 o0; o0.x = a0x * s0; o0.y = a0y * s0; o0.z = a0z * s0; o0.w = a0w * s0;
    float4 o1; o1.x = a1x * s1; o1.y = a1y * s1; o1.z = a1z * s1; o1.w = a1w * s1;
    *(float4*)ao = o0;
    *(float4*)(ao + 128) = o1;
  }
}

// ================================================================
// K7: epilogue per distinct ctx row (2208 rows), 4/block. grid=552.
// ================================================================
__global__ __launch_bounds__(128) void k7_epilogue(
    const float* __restrict__ mow, const float* __restrict__ mob,
    const float* __restrict__ roww, const float* __restrict__ robb,
    const float* __restrict__ qw,  const float* __restrict__ qb,
    float* __restrict__ ws)
{
  __shared__ float ao_s[4][128];
  __shared__ float t1[4][128];
  __shared__ float red2[4][2];
  const int t  = threadIdx.x;
  const int r0 = blockIdx.x * 4;

  int aooff[4], x1off[4];
  #pragma unroll
  for (int i = 0; i < 4; ++i) {
    int r = r0 + i;
    if (r < 768) { aooff[i] = OFF_AOE + r * 128; x1off[i] = OFF_XE + r * 128; }
    else {
      int rr = r - 768;
      int jx = rr / 96, l96 = rr % 96;
      int b = l96 >> 1, s = l96 & 1;
      int ag = s ? (jx + 1) : jx;
      aooff[i] = OFF_AOA + rr * 128;
      x1off[i] = OFF_XA + (b * 16 + ag) * 128;
    }
  }
  for (int f = t; f < 512; f += 128) { int i = f >> 7, c = f & 127; ao_s[i][c] = ws[aooff[i] + c]; }
  __syncthreads();

  { // out_proj + residual
    const int o = t;
    const float bo = mob[o];
    float acc[4] = {bo, bo, bo, bo};
    const float4* wr = (const float4*)(mow + o * 128);
    #pragma unroll 8
    for (int kk = 0; kk < 32; ++kk) {
      float4 w = wr[kk];
      const int k = kk * 4;
      #pragma unroll
      for (int i = 0; i < 4; ++i) {
        acc[i] = fmaf(ao_s[i][k], w.x, acc[i]); acc[i] = fmaf(ao_s[i][k+1], w.y, acc[i]);
        acc[i] = fmaf(ao_s[i][k+2], w.z, acc[i]); acc[i] = fmaf(ao_s[i][k+3], w.w, acc[i]);
      }
    }
    #pragma unroll
    for (int i = 0; i < 4; ++i) t1[i][o] = acc[i] + ws[x1off[i] + o];
  }
  __syncthreads();

  float c4[4];
  { // ctx = relu(row @ t1 + rob)
    const int o = t;
    const float bo = robb[o];
    float acc[4] = {bo, bo, bo, bo};
    const float4* wr = (const float4*)(roww + o * 128);
    #pragma unroll 8
    for (int kk = 0; kk < 32; ++kk) {
      float4 w = wr[kk];
      const int k = kk * 4;
      #pragma unroll
      for (int i = 0; i < 4; ++i) {
        acc[i] = fmaf(t1[i][k], w.x, acc[i]); acc[i] = fmaf(t1[i][k+1], w.y, acc[i]);
        acc[i] = fmaf(t1[i][k+2], w.z, acc[i]); acc[i] = fmaf(t1[i][k+3], w.w, acc[i]);
      }
    }
    #pragma unroll
    for (int i = 0; i < 4; ++i) c4[i] = fmaxf(acc[i], 0.f);
  }

  const float qwt = qw[t];
  #pragma unroll
  for (int i = 0; i < 4; ++i) {
    float v = qwt * c4[i];
    v += __shfl_down(v, 32); v += __shfl_down(v, 16); v += __shfl_down(v, 8);
    v += __shfl_down(v, 4);  v += __shfl_down(v, 2);  v += __shfl_down(v, 1);
    if ((t & 63) == 0) red2[i][t >> 6] = v;
  }
  __syncthreads();
  if (t < 4) {
    float qv = red2[t][0] + red2[t][1] + qb[0];
    int r = r0 + t;
    if (r < 768) ws[OFF_QVE + r] = qv;
    else         ws[OFF_QVA + (r - 768)] = qv;
  }
}

// ================================================================
// K8: q_values[b,i] = qv_e[b,i] + sum_j qv_a
// ================================================================
__global__ __launch_bounds__(256) void k8_final(const float* __restrict__ ws, float* __restrict__ out)
{
  const int idx = blockIdx.x * 256 + threadIdx.x;
  if (idx >= 768) return;
  const int b = idx >> 4, i = idx & 15;
  float acc = ws[OFF_QVE + idx];
  const float* qva = ws + OFF_QVA;
  #pragma unroll
  for (int j = 1; j <= 15; ++j) {
    int s = (i >= j) ? 0 : 1;
    acc += qva[(j - 1) * 96 + b * 2 + s];
  }
  out[OUT_QV + idx] = acc;
}

// ================================================================
extern "C" void kernel_launch(void* const* d_in, const int* in_sizes, int n_in,
                              void* d_out, int out_size, void* d_ws, size_t ws_size,
                              hipStream_t stream)
{
  (void)in_sizes; (void)n_in; (void)out_size;
  if (ws_size < (size_t)WS_FLOATS * 4) return;  // fail loudly (out stays zero/poison)

  const float* obs = (const float*)d_in[0];
  const float* aw1 = (const float*)d_in[1];
  const float* ab1 = (const float*)d_in[2];
  const float* aw2 = (const float*)d_in[3];
  const float* ab2 = (const float*)d_in[4];
  const float* aw3 = (const float*)d_in[5];
  const float* ab3 = (const float*)d_in[6];
  const float* eow = (const float*)d_in[7];
  const float* eob = (const float*)d_in[8];
  const float* eaw = (const float*)d_in[9];
  const float* eab = (const float*)d_in[10];
  const float* riw = (const float*)d_in[11];
  const float* rib = (const float*)d_in[12];
  const float* roww= (const float*)d_in[13];
  const float* robb= (const float*)d_in[14];
  const float* miw = (const float*)d_in[15];
  const float* mib = (const float*)d_in[16];
  const float* mow = (const float*)d_in[17];
  const float* mob = (const float*)d_in[18];
  const float* qw  = (const float*)d_in[19];
  const float* qb  = (const float*)d_in[20];

  float* out = (float*)d_out;
  float* ws  = (float*)d_ws;

  k1_actor_enc<<<dim3(384), dim3(256), 0, stream>>>(obs, aw1, ab1, aw2, ab2, aw3, ab3,
                                                    eow, eob, eaw, eab, out, ws);
  k2_rsa_in<<<dim3(384), dim3(256), 0, stream>>>(riw, rib, miw, mib, ws);
  k3_scores_e<<<dim3(12, 12, 4), dim3(256), 0, stream>>>(ws);
  k5_softmax_av_e<<<dim3(48, 4), dim3(256), 0, stream>>>(ws);
  k6_a_slices<<<dim3(120), dim3(256), 0, stream>>>(ws);
  k7_epilogue<<<dim3(552), dim3(128), 0, stream>>>(mow, mob, roww, robb, qw, qb, ws);
  k8_final<<<dim3(3), dim3(256), 0, stream>>>(ws, out);
}

// Round 6
// 227.996 us; speedup vs baseline: 1.0788x; 1.0788x over previous
//
#include <hip/hip_runtime.h>
#include <math.h>

typedef unsigned int u32;

static __device__ __forceinline__ float lrelu(float x){ return x > 0.f ? x : 0.01f * x; }

// ---- workspace layout (float offsets) ----
#define OFF_EO    0         // 768*128
#define OFF_EA    98304     // 768*128
#define OFF_XE    196608    // 768*128
#define OFF_XA    294912    // 768*128
#define OFF_QKVE  393216    // 768*384
#define OFF_QKVA  688128    // 768*384
#define OFF_AOE   983040    // 768*128
#define OFF_AOA   1081344   // 15*96*128
#define OFF_QVE   1265664   // 768
#define OFF_QVA   1266432   // 15*96
#define WS_FLOATS 1267872   // ~5.1 MB (S_e eliminated)

// ---- output layout (fp32 elems) ----
#define OUT_POL 0
#define OUT_QV  24576
#define OUT_EO  25344

#define SCALE_ATTN 0.17677669529663689f  // 1/sqrt(32)

// ================================================================
// K1: actor (3 layers + gelu) + obs encoder + obs-act encoder.
// 2 rows (b,n) per block, 256 threads. grid=384.
// ================================================================
__global__ __launch_bounds__(256) void k1_actor_enc(
    const float* __restrict__ obs,
    const float* __restrict__ aw1, const float* __restrict__ ab1,
    const float* __restrict__ aw2, const float* __restrict__ ab2,
    const float* __restrict__ aw3, const float* __restrict__ ab3,
    const float* __restrict__ eow, const float* __restrict__ eob,
    const float* __restrict__ eaw, const float* __restrict__ eab,
    float* __restrict__ out, float* __restrict__ ws)
{
  __shared__ float obs_s[2][128];
  __shared__ float h1[2][256];
  __shared__ float h2[2][128];
  __shared__ float pol[2][32];
  const int t  = threadIdx.x;
  const int r0 = blockIdx.x * 2;

  { int r = t >> 7, k = t & 127;
    obs_s[r][k] = obs[(r0 + r) * 128 + k]; }
  __syncthreads();

  { // layer1: 256 outputs x 2 rows
    const int o = t;
    float a0 = ab1[o]; float a1 = a0;
    const float4* wr = (const float4*)(aw1 + o * 128);
    #pragma unroll 8
    for (int kk = 0; kk < 32; ++kk) {
      float4 w = wr[kk];
      const int k = kk * 4;
      a0 = fmaf(obs_s[0][k], w.x, a0); a0 = fmaf(obs_s[0][k+1], w.y, a0);
      a0 = fmaf(obs_s[0][k+2], w.z, a0); a0 = fmaf(obs_s[0][k+3], w.w, a0);
      a1 = fmaf(obs_s[1][k], w.x, a1); a1 = fmaf(obs_s[1][k+1], w.y, a1);
      a1 = fmaf(obs_s[1][k+2], w.z, a1); a1 = fmaf(obs_s[1][k+3], w.w, a1);
    }
    h1[0][o] = lrelu(a0); h1[1][o] = lrelu(a1);
  }
  __syncthreads();

  if (t < 128) { // layer2: 128 outputs x 2 rows
    const int o = t;
    float a0 = ab2[o]; float a1 = a0;
    const float4* wr = (const float4*)(aw2 + o * 256);
    #pragma unroll 8
    for (int kk = 0; kk < 64; ++kk) {
      float4 w = wr[kk];
      const int k = kk * 4;
      a0 = fmaf(h1[0][k], w.x, a0); a0 = fmaf(h1[0][k+1], w.y, a0);
      a0 = fmaf(h1[0][k+2], w.z, a0); a0 = fmaf(h1[0][k+3], w.w, a0);
      a1 = fmaf(h1[1][k], w.x, a1); a1 = fmaf(h1[1][k+1], w.y, a1);
      a1 = fmaf(h1[1][k+2], w.z, a1); a1 = fmaf(h1[1][k+3], w.w, a1);
    }
    h2[0][o] = lrelu(a0); h2[1][o] = lrelu(a1);
  }
  __syncthreads();

  if (t < 64) { // layer3 + exact GELU -> policy
    const int o = t & 31, r = t >> 5;
    float a = ab3[o];
    const float4* wr = (const float4*)(aw3 + o * 128);
    #pragma unroll 8
    for (int kk = 0; kk < 32; ++kk) {
      float4 w = wr[kk];
      const int k = kk * 4;
      a = fmaf(h2[r][k], w.x, a); a = fmaf(h2[r][k+1], w.y, a);
      a = fmaf(h2[r][k+2], w.z, a); a = fmaf(h2[r][k+3], w.w, a);
    }
    float g = 0.5f * a * (1.f + erff(a * 0.70710678118654752f));
    pol[r][o] = g;
    out[OUT_POL + (r0 + r) * 32 + o] = g;
  }
  __syncthreads();

  if (t < 128) { // eo = obs @ eow^T + eob
    const int o = t;
    float a0 = eob[o]; float a1 = a0;
    const float4* wr = (const float4*)(eow + o * 128);
    #pragma unroll 8
    for (int kk = 0; kk < 32; ++kk) {
      float4 w = wr[kk];
      const int k = kk * 4;
      a0 = fmaf(obs_s[0][k], w.x, a0); a0 = fmaf(obs_s[0][k+1], w.y, a0);
      a0 = fmaf(obs_s[0][k+2], w.z, a0); a0 = fmaf(obs_s[0][k+3], w.w, a0);
      a1 = fmaf(obs_s[1][k], w.x, a1); a1 = fmaf(obs_s[1][k+1], w.y, a1);
      a1 = fmaf(obs_s[1][k+2], w.z, a1); a1 = fmaf(obs_s[1][k+3], w.w, a1);
    }
    ws[OFF_EO + (r0 + 0) * 128 + o] = a0;
    ws[OFF_EO + (r0 + 1) * 128 + o] = a1;
    out[OUT_EO + (r0 + 0) * 128 + o] = a0;
    out[OUT_EO + (r0 + 1) * 128 + o] = a1;
  } else {       // ea = [obs, policy] @ eaw^T + eab
    const int o = t - 128;
    float a0 = eab[o]; float a1 = a0;
    const float4* wr = (const float4*)(eaw + o * 160);  // 40 float4
    #pragma unroll 8
    for (int kk = 0; kk < 32; ++kk) {
      float4 w = wr[kk];
      const int k = kk * 4;
      a0 = fmaf(obs_s[0][k], w.x, a0); a0 = fmaf(obs_s[0][k+1], w.y, a0);
      a0 = fmaf(obs_s[0][k+2], w.z, a0); a0 = fmaf(obs_s[0][k+3], w.w, a0);
      a1 = fmaf(obs_s[1][k], w.x, a1); a1 = fmaf(obs_s[1][k+1], w.y, a1);
      a1 = fmaf(obs_s[1][k+2], w.z, a1); a1 = fmaf(obs_s[1][k+3], w.w, a1);
    }
    #pragma unroll
    for (int kk = 32; kk < 40; ++kk) {
      float4 w = wr[kk];
      const int k = kk * 4 - 128;
      a0 = fmaf(pol[0][k], w.x, a0); a0 = fmaf(pol[0][k+1], w.y, a0);
      a0 = fmaf(pol[0][k+2], w.z, a0); a0 = fmaf(pol[0][k+3], w.w, a0);
      a1 = fmaf(pol[1][k], w.x, a1); a1 = fmaf(pol[1][k+1], w.y, a1);
      a1 = fmaf(pol[1][k+2], w.z, a1); a1 = fmaf(pol[1][k+3], w.w, a1);
    }
    ws[OFF_EA + (r0 + 0) * 128 + o] = a0;
    ws[OFF_EA + (r0 + 1) * 128 + o] = a1;
  }
}

// ================================================================
// K2: x = relu(riw@in + rib); qkv = miw@x + mib. grid=384.
// NOTE: 768 is NOT pow2 -> subtraction, not &767.
// ================================================================
__global__ __launch_bounds__(256) void k2_rsa_in(
    const float* __restrict__ riw, const float* __restrict__ rib,
    const float* __restrict__ miw, const float* __restrict__ mib,
    float* __restrict__ ws)
{
  __shared__ float xin[4][128];
  __shared__ float xx[4][128];
  const int t  = threadIdx.x;
  const int R0 = blockIdx.x * 4;
  const int which = (R0 >= 768);
  const int r    = which ? (R0 - 768) : R0;
  const float* inb = ws + (which ? OFF_EA : OFF_EO) + r * 128;
  float* xout = ws + (which ? OFF_XA : OFF_XE) + r * 128;
  float* qout = ws + (which ? OFF_QKVA : OFF_QKVE) + (size_t)r * 384;

  for (int f = t; f < 512; f += 256) xin[f >> 7][f & 127] = inb[f];
  __syncthreads();

  { // x phase
    const int o = t & 127, p = (t >> 7) * 2;
    float a0 = rib[o]; float a1 = a0;
    const float4* wr = (const float4*)(riw + o * 128);
    #pragma unroll 8
    for (int kk = 0; kk < 32; ++kk) {
      float4 w = wr[kk];
      const int k = kk * 4;
      a0 = fmaf(xin[p][k], w.x, a0); a0 = fmaf(xin[p][k+1], w.y, a0);
      a0 = fmaf(xin[p][k+2], w.z, a0); a0 = fmaf(xin[p][k+3], w.w, a0);
      a1 = fmaf(xin[p+1][k], w.x, a1); a1 = fmaf(xin[p+1][k+1], w.y, a1);
      a1 = fmaf(xin[p+1][k+2], w.z, a1); a1 = fmaf(xin[p+1][k+3], w.w, a1);
    }
    a0 = fmaxf(a0, 0.f); a1 = fmaxf(a1, 0.f);
    xx[p][o] = a0; xx[p + 1][o] = a1;
    xout[p * 128 + o] = a0; xout[(p + 1) * 128 + o] = a1;
  }
  __syncthreads();

  #pragma unroll
  for (int p3 = 0; p3 < 3; ++p3) {
    const int o = p3 * 128 + (t & 127), p = (t >> 7) * 2;
    float a0 = mib[o]; float a1 = a0;
    const float4* wr = (const float4*)(miw + o * 128);
    #pragma unroll 8
    for (int kk = 0; kk < 32; ++kk) {
      float4 w = wr[kk];
      const int k = kk * 4;
      a0 = fmaf(xx[p][k], w.x, a0); a0 = fmaf(xx[p][k+1], w.y, a0);
      a0 = fmaf(xx[p][k+2], w.z, a0); a0 = fmaf(xx[p][k+3], w.w, a0);
      a1 = fmaf(xx[p+1][k], w.x, a1); a1 = fmaf(xx[p+1][k+1], w.y, a1);
      a1 = fmaf(xx[p+1][k+2], w.z, a1); a1 = fmaf(xx[p+1][k+3], w.w, a1);
    }
    qout[(size_t)p * 384 + o] = a0;
    qout[(size_t)(p + 1) * 384 + o] = a1;
  }
}

// ================================================================
// K35: slice j=0 FLASH attention (replaces k3 scores + k5 softmax/PV).
// Block = (16 q-rows, head), grid (48, 4), 256 threads.
// Online softmax; row state rm/rs touched only by same-wave lanes.
// ================================================================
__global__ __launch_bounds__(256) void k35_flash_e(float* __restrict__ ws)
{
  __shared__ float Qs[16 * 33];
  __shared__ float Ks[64 * 33];
  __shared__ float Vs[64 * 33];
  __shared__ float Ss[16 * 68];
  __shared__ float rm[16], rs[16];
  const int t  = threadIdx.x;
  const int l0 = blockIdx.x * 16, h = blockIdx.y;
  const float* qkve = ws + OFF_QKVE;

  for (int f = t; f < 512; f += 256)
    Qs[(f >> 5) * 33 + (f & 31)] = qkve[(size_t)(l0 + (f >> 5)) * 384 + h * 32 + (f & 31)];
  if (t < 16) { rm[t] = -1e30f; rs[t] = 0.f; }

  const int l  = t >> 4;        // row 0..15  (16 consecutive lanes per row -> same wave)
  const int c0 = (t & 15) * 4;  // score cols for this thread
  const int d2 = t & 15;        // O dims d2, d2+16
  float o0 = 0.f, o1 = 0.f;
  __syncthreads();

  for (int mt = 0; mt < 12; ++mt) {
    const int m0 = mt * 64;
    for (int f = t; f < 2048; f += 256) {
      int i = f >> 5, d = f & 31;
      const float* src = qkve + (size_t)(m0 + i) * 384 + h * 32 + d;
      Ks[i * 33 + d] = src[128];
      Vs[i * 33 + d] = src[256];
    }
    __syncthreads();

    // scores: 4 per thread (row l, cols c0..c0+3)
    float s0 = 0.f, s1 = 0.f, s2 = 0.f, s3 = 0.f;
    #pragma unroll
    for (int d = 0; d < 32; ++d) {
      float q = Qs[l * 33 + d];
      s0 = fmaf(q, Ks[(c0 + 0) * 33 + d], s0);
      s1 = fmaf(q, Ks[(c0 + 1) * 33 + d], s1);
      s2 = fmaf(q, Ks[(c0 + 2) * 33 + d], s2);
      s3 = fmaf(q, Ks[(c0 + 3) * 33 + d], s3);
    }
    s0 *= SCALE_ATTN; s1 *= SCALE_ATTN; s2 *= SCALE_ATTN; s3 *= SCALE_ATTN;

    // tile max over the 64 cols of row l (16-lane butterfly)
    float tmax = fmaxf(fmaxf(s0, s1), fmaxf(s2, s3));
    #pragma unroll
    for (int off = 1; off < 16; off <<= 1)
      tmax = fmaxf(tmax, __shfl_xor(tmax, off, 64));

    const float mold = rm[l];                 // all 16 lanes read (in-wave, pre-update)
    const float mnew = fmaxf(mold, tmax);
    const float alpha = expf(mold - mnew);

    s0 = expf(s0 - mnew); s1 = expf(s1 - mnew);
    s2 = expf(s2 - mnew); s3 = expf(s3 - mnew);
    Ss[l * 68 + c0 + 0] = s0; Ss[l * 68 + c0 + 1] = s1;
    Ss[l * 68 + c0 + 2] = s2; Ss[l * 68 + c0 + 3] = s3;
    float psum = s0 + s1 + s2 + s3;
    #pragma unroll
    for (int off = 1; off < 16; off <<= 1) psum += __shfl_xor(psum, off, 64);
    if ((t & 15) == 0) { rm[l] = mnew; rs[l] = rs[l] * alpha + psum; }

    // O update (reads Ss written by same-wave lanes; broadcast across row)
    o0 *= alpha; o1 *= alpha;
    #pragma unroll 8
    for (int k = 0; k < 64; ++k) {
      float p = Ss[l * 68 + k];
      o0 = fmaf(p, Vs[k * 33 + d2], o0);
      o1 = fmaf(p, Vs[k * 33 + d2 + 16], o1);
    }
    __syncthreads();
  }

  const float inv = 1.f / rs[l];   // rs final value written by same wave
  float* aoe = ws + OFF_AOE;
  aoe[(size_t)(l0 + l) * 128 + h * 32 + d2]      = o0 * inv;
  aoe[(size_t)(l0 + l) * 128 + h * 32 + d2 + 16] = o1 * inv;
}

// ================================================================
// K6: slices j=1..15, dedup'd weighted softmax. grid=120.
// ================================================================
__global__ __launch_bounds__(256) void k6_a_slices(float* __restrict__ ws)
{
  __shared__ float Qb[48 * 33];
  __shared__ float Ka[96 * 33];
  __shared__ __align__(16) float Va[96 * 36];
  __shared__ float Ss[48 * 97];
  __shared__ float rinv[48];
  const int t  = threadIdx.x;
  const int z  = blockIdx.x;
  const int j1 = z >> 3;            // 0..14
  const int h  = (z & 7) >> 1, rb = z & 1;
  const int jj = j1 + 1;            // slice 1..15
  const float* qkva = ws + OFF_QKVA;

  for (int f = t; f < 3072; f += 256) {
    int ml = f >> 5, d = f & 31;
    int bp = ml >> 1, sp = ml & 1;
    int ag = sp ? jj : (jj - 1);
    const float* src = qkva + (size_t)(bp * 16 + ag) * 384 + h * 32 + d;
    Ka[ml * 33 + d] = src[128];
    Va[ml * 36 + d] = src[256];
  }
  for (int f = t; f < 1536; f += 256) {
    int ql = f >> 5, d = f & 31;
    int Lb = rb * 48 + ql;
    int b = Lb >> 1, s = Lb & 1;
    int ag = s ? jj : (jj - 1);
    Qb[ql * 33 + d] = qkva[(size_t)(b * 16 + ag) * 384 + h * 32 + d];
  }
  __syncthreads();

  { // scores 48x96
    const int tl = (t >> 4) * 3, tm = (t & 15) * 6;
    float acc[3][6] = {{0.f}};
    #pragma unroll
    for (int d = 0; d < 32; ++d) {
      float q[3], k[6];
      #pragma unroll
      for (int r = 0; r < 3; ++r) q[r] = Qb[(tl + r) * 33 + d];
      #pragma unroll
      for (int c = 0; c < 6; ++c) k[c] = Ka[(tm + c) * 33 + d];
      #pragma unroll
      for (int r = 0; r < 3; ++r)
        #pragma unroll
        for (int c = 0; c < 6; ++c) acc[r][c] = fmaf(q[r], k[c], acc[r][c]);
    }
    #pragma unroll
    for (int r = 0; r < 3; ++r)
      #pragma unroll
      for (int c = 0; c < 6; ++c) Ss[(tl + r) * 97 + tm + c] = acc[r][c] * SCALE_ATTN;
  }
  __syncthreads();

  if (t < 48) { // weighted softmax per row
    float* rowp = Ss + t * 97;
    float mx = rowp[0];
    for (int m = 1; m < 96; ++m) mx = fmaxf(mx, rowp[m]);
    const float wj = (float)jj, wnj = (float)(16 - jj);
    float sum = 0.f;
    for (int m = 0; m < 96; ++m) {
      float w = (m & 1) ? wj : wnj;
      float p = w * expf(rowp[m] - mx);
      rowp[m] = p; sum += p;
    }
    rinv[t] = 1.f / sum;
  }
  __syncthreads();

  if (t < 192) { // P@V
    const int l0 = (t >> 3) * 2, d0 = (t & 7) * 4;
    float a0x=0.f,a0y=0.f,a0z=0.f,a0w=0.f, a1x=0.f,a1y=0.f,a1z=0.f,a1w=0.f;
    for (int m = 0; m < 96; ++m) {
      float p0 = Ss[l0 * 97 + m], p1 = Ss[(l0 + 1) * 97 + m];
      float4 v = *(const float4*)&Va[m * 36 + d0];
      a0x = fmaf(p0, v.x, a0x); a0y = fmaf(p0, v.y, a0y);
      a0z = fmaf(p0, v.z, a0z); a0w = fmaf(p0, v.w, a0w);
      a1x = fmaf(p1, v.x, a1x); a1y = fmaf(p1, v.y, a1y);
      a1z = fmaf(p1, v.z, a1z); a1w = fmaf(p1, v.w, a1w);
    }
    const float s0 = rinv[l0], s1 = rinv[l0 + 1];
    float* ao = ws + OFF_AOA + (size_t)(j1 * 96 + rb * 48 + l0) * 128 + h * 32 + d0;
    float4 o0; o0.x = a0x * s0; o0.y = a0y * s0; o0.z = a0z * s0; o0.w = a0w * s0;
    float4 o1; o1.x = a1x * s1; o1.y = a1y * s1; o1.z = a1z * s1; o1.w = a1w * s1;
    *(float4*)ao = o0;
    *(float4*)(ao + 128) = o1;
  }
}

// ================================================================
// K7: epilogue per distinct ctx row (2208 rows), 4/block. grid=552.
// ================================================================
__global__ __launch_bounds__(128) void k7_epilogue(
    const float* __restrict__ mow, const float* __restrict__ mob,
    const float* __restrict__ roww, const float* __restrict__ robb,
    const float* __restrict__ qw,  const float* __restrict__ qb,
    float* __restrict__ ws)
{
  __shared__ float ao_s[4][128];
  __shared__ float t1[4][128];
  __shared__ float red2[4][2];
  const int t  = threadIdx.x;
  const int r0 = blockIdx.x * 4;

  int aooff[4], x1off[4];
  #pragma unroll
  for (int i = 0; i < 4; ++i) {
    int r = r0 + i;
    if (r < 768) { aooff[i] = OFF_AOE + r * 128; x1off[i] = OFF_XE + r * 128; }
    else {
      int rr = r - 768;
      int jx = rr / 96, l96 = rr % 96;
      int b = l96 >> 1, s = l96 & 1;
      int ag = s ? (jx + 1) : jx;
      aooff[i] = OFF_AOA + rr * 128;
      x1off[i] = OFF_XA + (b * 16 + ag) * 128;
    }
  }
  for (int f = t; f < 512; f += 128) { int i = f >> 7, c = f & 127; ao_s[i][c] = ws[aooff[i] + c]; }
  __syncthreads();

  { // out_proj + residual
    const int o = t;
    const float bo = mob[o];
    float acc[4] = {bo, bo, bo, bo};
    const float4* wr = (const float4*)(mow + o * 128);
    #pragma unroll 8
    for (int kk = 0; kk < 32; ++kk) {
      float4 w = wr[kk];
      const int k = kk * 4;
      #pragma unroll
      for (int i = 0; i < 4; ++i) {
        acc[i] = fmaf(ao_s[i][k], w.x, acc[i]); acc[i] = fmaf(ao_s[i][k+1], w.y, acc[i]);
        acc[i] = fmaf(ao_s[i][k+2], w.z, acc[i]); acc[i] = fmaf(ao_s[i][k+3], w.w, acc[i]);
      }
    }
    #pragma unroll
    for (int i = 0; i < 4; ++i) t1[i][o] = acc[i] + ws[x1off[i] + o];
  }
  __syncthreads();

  float c4[4];
  { // ctx = relu(row @ t1 + rob)
    const int o = t;
    const float bo = robb[o];
    float acc[4] = {bo, bo, bo, bo};
    const float4* wr = (const float4*)(roww + o * 128);
    #pragma unroll 8
    for (int kk = 0; kk < 32; ++kk) {
      float4 w = wr[kk];
      const int k = kk * 4;
      #pragma unroll
      for (int i = 0; i < 4; ++i) {
        acc[i] = fmaf(t1[i][k], w.x, acc[i]); acc[i] = fmaf(t1[i][k+1], w.y, acc[i]);
        acc[i] = fmaf(t1[i][k+2], w.z, acc[i]); acc[i] = fmaf(t1[i][k+3], w.w, acc[i]);
      }
    }
    #pragma unroll
    for (int i = 0; i < 4; ++i) c4[i] = fmaxf(acc[i], 0.f);
  }

  const float qwt = qw[t];
  #pragma unroll
  for (int i = 0; i < 4; ++i) {
    float v = qwt * c4[i];
    v += __shfl_down(v, 32); v += __shfl_down(v, 16); v += __shfl_down(v, 8);
    v += __shfl_down(v, 4);  v += __shfl_down(v, 2);  v += __shfl_down(v, 1);
    if ((t & 63) == 0) red2[i][t >> 6] = v;
  }
  __syncthreads();
  if (t < 4) {
    float qv = red2[t][0] + red2[t][1] + qb[0];
    int r = r0 + t;
    if (r < 768) ws[OFF_QVE + r] = qv;
    else         ws[OFF_QVA + (r - 768)] = qv;
  }
}

// ================================================================
// K8: q_values[b,i] = qv_e[b,i] + sum_j qv_a
// ================================================================
__global__ __launch_bounds__(256) void k8_final(const float* __restrict__ ws, float* __restrict__ out)
{
  const int idx = blockIdx.x * 256 + threadIdx.x;
  if (idx >= 768) return;
  const int b = idx >> 4, i = idx & 15;
  float acc = ws[OFF_QVE + idx];
  const float* qva = ws + OFF_QVA;
  #pragma unroll
  for (int j = 1; j <= 15; ++j) {
    int s = (i >= j) ? 0 : 1;
    acc += qva[(j - 1) * 96 + b * 2 + s];
  }
  out[OUT_QV + idx] = acc;
}

// ================================================================
extern "C" void kernel_launch(void* const* d_in, const int* in_sizes, int n_in,
                              void* d_out, int out_size, void* d_ws, size_t ws_size,
                              hipStream_t stream)
{
  (void)in_sizes; (void)n_in; (void)out_size;
  if (ws_size < (size_t)WS_FLOATS * 4) return;

  const float* obs = (const float*)d_in[0];
  const float* aw1 = (const float*)d_in[1];
  const float* ab1 = (const float*)d_in[2];
  const float* aw2 = (const float*)d_in[3];
  const float* ab2 = (const float*)d_in[4];
  const float* aw3 = (const float*)d_in[5];
  const float* ab3 = (const float*)d_in[6];
  const float* eow = (const float*)d_in[7];
  const float* eob = (const float*)d_in[8];
  const float* eaw = (const float*)d_in[9];
  const float* eab = (const float*)d_in[10];
  const float* riw = (const float*)d_in[11];
  const float* rib = (const float*)d_in[12];
  const float* roww= (const float*)d_in[13];
  const float* robb= (const float*)d_in[14];
  const float* miw = (const float*)d_in[15];
  const float* mib = (const float*)d_in[16];
  const float* mow = (const float*)d_in[17];
  const float* mob = (const float*)d_in[18];
  const float* qw  = (const float*)d_in[19];
  const float* qb  = (const float*)d_in[20];

  float* out = (float*)d_out;
  float* ws  = (float*)d_ws;

  k1_actor_enc<<<dim3(384), dim3(256), 0, stream>>>(obs, aw1, ab1, aw2, ab2, aw3, ab3,
                                                    eow, eob, eaw, eab, out, ws);
  k2_rsa_in<<<dim3(384), dim3(256), 0, stream>>>(riw, rib, miw, mib, ws);
  k35_flash_e<<<dim3(48, 4), dim3(256), 0, stream>>>(ws);
  k6_a_slices<<<dim3(120), dim3(256), 0, stream>>>(ws);
  k7_epilogue<<<dim3(552), dim3(128), 0, stream>>>(mow, mob, roww, robb, qw, qb, ws);
  k8_final<<<dim3(3), dim3(256), 0, stream>>>(ws, out);
}

// Round 7
// 199.479 us; speedup vs baseline: 1.2330x; 1.1430x over previous
//
#include <hip/hip_runtime.h>
#include <math.h>

typedef unsigned int u32;

static __device__ __forceinline__ float lrelu(float x){ return x > 0.f ? x : 0.01f * x; }

// ---- workspace layout (float offsets) ----
#define OFF_EO    0         // 768*128
#define OFF_EA    98304     // 768*128
#define OFF_XE    196608    // 768*128
#define OFF_XA    294912    // 768*128
#define OFF_QKVE  393216    // 768*384
#define OFF_QKVA  688128    // 768*384
#define OFF_AOP   983040    // 4 splits * 768*128 (e-slice partial O, unnormalized)
#define OFF_DEN   1376256   // 4 splits * 768*4  (per-row per-head partial denom)
#define OFF_AOA   1388544   // 15*96*128
#define OFF_QVE   1572864   // 768
#define OFF_QVA   1573632   // 15*96 (pad)
#define WS_FLOATS 1575072   // ~6.3 MB

// ---- output layout (fp32 elems) ----
#define OUT_POL 0
#define OUT_QV  24576
#define OUT_EO  25344

#define SCALE_ATTN 0.17677669529663689f  // 1/sqrt(32)

// ================================================================
// K1: actor (3 layers + gelu) + obs encoder + obs-act encoder.
// ================================================================
__global__ __launch_bounds__(256) void k1_actor_enc(
    const float* __restrict__ obs,
    const float* __restrict__ aw1, const float* __restrict__ ab1,
    const float* __restrict__ aw2, const float* __restrict__ ab2,
    const float* __restrict__ aw3, const float* __restrict__ ab3,
    const float* __restrict__ eow, const float* __restrict__ eob,
    const float* __restrict__ eaw, const float* __restrict__ eab,
    float* __restrict__ out, float* __restrict__ ws)
{
  __shared__ float obs_s[2][128];
  __shared__ float h1[2][256];
  __shared__ float h2[2][128];
  __shared__ float pol[2][32];
  const int t  = threadIdx.x;
  const int r0 = blockIdx.x * 2;

  { int r = t >> 7, k = t & 127;
    obs_s[r][k] = obs[(r0 + r) * 128 + k]; }
  __syncthreads();

  { // layer1
    const int o = t;
    float a0 = ab1[o]; float a1 = a0;
    const float4* wr = (const float4*)(aw1 + o * 128);
    #pragma unroll 8
    for (int kk = 0; kk < 32; ++kk) {
      float4 w = wr[kk];
      const int k = kk * 4;
      a0 = fmaf(obs_s[0][k], w.x, a0); a0 = fmaf(obs_s[0][k+1], w.y, a0);
      a0 = fmaf(obs_s[0][k+2], w.z, a0); a0 = fmaf(obs_s[0][k+3], w.w, a0);
      a1 = fmaf(obs_s[1][k], w.x, a1); a1 = fmaf(obs_s[1][k+1], w.y, a1);
      a1 = fmaf(obs_s[1][k+2], w.z, a1); a1 = fmaf(obs_s[1][k+3], w.w, a1);
    }
    h1[0][o] = lrelu(a0); h1[1][o] = lrelu(a1);
  }
  __syncthreads();

  if (t < 128) { // layer2
    const int o = t;
    float a0 = ab2[o]; float a1 = a0;
    const float4* wr = (const float4*)(aw2 + o * 256);
    #pragma unroll 8
    for (int kk = 0; kk < 64; ++kk) {
      float4 w = wr[kk];
      const int k = kk * 4;
      a0 = fmaf(h1[0][k], w.x, a0); a0 = fmaf(h1[0][k+1], w.y, a0);
      a0 = fmaf(h1[0][k+2], w.z, a0); a0 = fmaf(h1[0][k+3], w.w, a0);
      a1 = fmaf(h1[1][k], w.x, a1); a1 = fmaf(h1[1][k+1], w.y, a1);
      a1 = fmaf(h1[1][k+2], w.z, a1); a1 = fmaf(h1[1][k+3], w.w, a1);
    }
    h2[0][o] = lrelu(a0); h2[1][o] = lrelu(a1);
  }
  __syncthreads();

  if (t < 64) { // layer3 + exact GELU
    const int o = t & 31, r = t >> 5;
    float a = ab3[o];
    const float4* wr = (const float4*)(aw3 + o * 128);
    #pragma unroll 8
    for (int kk = 0; kk < 32; ++kk) {
      float4 w = wr[kk];
      const int k = kk * 4;
      a = fmaf(h2[r][k], w.x, a); a = fmaf(h2[r][k+1], w.y, a);
      a = fmaf(h2[r][k+2], w.z, a); a = fmaf(h2[r][k+3], w.w, a);
    }
    float g = 0.5f * a * (1.f + erff(a * 0.70710678118654752f));
    pol[r][o] = g;
    out[OUT_POL + (r0 + r) * 32 + o] = g;
  }
  __syncthreads();

  if (t < 128) { // eo
    const int o = t;
    float a0 = eob[o]; float a1 = a0;
    const float4* wr = (const float4*)(eow + o * 128);
    #pragma unroll 8
    for (int kk = 0; kk < 32; ++kk) {
      float4 w = wr[kk];
      const int k = kk * 4;
      a0 = fmaf(obs_s[0][k], w.x, a0); a0 = fmaf(obs_s[0][k+1], w.y, a0);
      a0 = fmaf(obs_s[0][k+2], w.z, a0); a0 = fmaf(obs_s[0][k+3], w.w, a0);
      a1 = fmaf(obs_s[1][k], w.x, a1); a1 = fmaf(obs_s[1][k+1], w.y, a1);
      a1 = fmaf(obs_s[1][k+2], w.z, a1); a1 = fmaf(obs_s[1][k+3], w.w, a1);
    }
    ws[OFF_EO + (r0 + 0) * 128 + o] = a0;
    ws[OFF_EO + (r0 + 1) * 128 + o] = a1;
    out[OUT_EO + (r0 + 0) * 128 + o] = a0;
    out[OUT_EO + (r0 + 1) * 128 + o] = a1;
  } else {       // ea
    const int o = t - 128;
    float a0 = eab[o]; float a1 = a0;
    const float4* wr = (const float4*)(eaw + o * 160);
    #pragma unroll 8
    for (int kk = 0; kk < 32; ++kk) {
      float4 w = wr[kk];
      const int k = kk * 4;
      a0 = fmaf(obs_s[0][k], w.x, a0); a0 = fmaf(obs_s[0][k+1], w.y, a0);
      a0 = fmaf(obs_s[0][k+2], w.z, a0); a0 = fmaf(obs_s[0][k+3], w.w, a0);
      a1 = fmaf(obs_s[1][k], w.x, a1); a1 = fmaf(obs_s[1][k+1], w.y, a1);
      a1 = fmaf(obs_s[1][k+2], w.z, a1); a1 = fmaf(obs_s[1][k+3], w.w, a1);
    }
    #pragma unroll
    for (int kk = 32; kk < 40; ++kk) {
      float4 w = wr[kk];
      const int k = kk * 4 - 128;
      a0 = fmaf(pol[0][k], w.x, a0); a0 = fmaf(pol[0][k+1], w.y, a0);
      a0 = fmaf(pol[0][k+2], w.z, a0); a0 = fmaf(pol[0][k+3], w.w, a0);
      a1 = fmaf(pol[1][k], w.x, a1); a1 = fmaf(pol[1][k+1], w.y, a1);
      a1 = fmaf(pol[1][k+2], w.z, a1); a1 = fmaf(pol[1][k+3], w.w, a1);
    }
    ws[OFF_EA + (r0 + 0) * 128 + o] = a0;
    ws[OFF_EA + (r0 + 1) * 128 + o] = a1;
  }
}

// ================================================================
// K2: x = relu(riw@in + rib); qkv = miw@x + mib. grid=384.
// ================================================================
__global__ __launch_bounds__(256) void k2_rsa_in(
    const float* __restrict__ riw, const float* __restrict__ rib,
    const float* __restrict__ miw, const float* __restrict__ mib,
    float* __restrict__ ws)
{
  __shared__ float xin[4][128];
  __shared__ float xx[4][128];
  const int t  = threadIdx.x;
  const int R0 = blockIdx.x * 4;
  const int which = (R0 >= 768);
  const int r    = which ? (R0 - 768) : R0;   // 768 not pow2: no masks!
  const float* inb = ws + (which ? OFF_EA : OFF_EO) + r * 128;
  float* xout = ws + (which ? OFF_XA : OFF_XE) + r * 128;
  float* qout = ws + (which ? OFF_QKVA : OFF_QKVE) + (size_t)r * 384;

  for (int f = t; f < 512; f += 256) xin[f >> 7][f & 127] = inb[f];
  __syncthreads();

  {
    const int o = t & 127, p = (t >> 7) * 2;
    float a0 = rib[o]; float a1 = a0;
    const float4* wr = (const float4*)(riw + o * 128);
    #pragma unroll 8
    for (int kk = 0; kk < 32; ++kk) {
      float4 w = wr[kk];
      const int k = kk * 4;
      a0 = fmaf(xin[p][k], w.x, a0); a0 = fmaf(xin[p][k+1], w.y, a0);
      a0 = fmaf(xin[p][k+2], w.z, a0); a0 = fmaf(xin[p][k+3], w.w, a0);
      a1 = fmaf(xin[p+1][k], w.x, a1); a1 = fmaf(xin[p+1][k+1], w.y, a1);
      a1 = fmaf(xin[p+1][k+2], w.z, a1); a1 = fmaf(xin[p+1][k+3], w.w, a1);
    }
    a0 = fmaxf(a0, 0.f); a1 = fmaxf(a1, 0.f);
    xx[p][o] = a0; xx[p + 1][o] = a1;
    xout[p * 128 + o] = a0; xout[(p + 1) * 128 + o] = a1;
  }
  __syncthreads();

  #pragma unroll
  for (int p3 = 0; p3 < 3; ++p3) {
    const int o = p3 * 128 + (t & 127), p = (t >> 7) * 2;
    float a0 = mib[o]; float a1 = a0;
    const float4* wr = (const float4*)(miw + o * 128);
    #pragma unroll 8
    for (int kk = 0; kk < 32; ++kk) {
      float4 w = wr[kk];
      const int k = kk * 4;
      a0 = fmaf(xx[p][k], w.x, a0); a0 = fmaf(xx[p][k+1], w.y, a0);
      a0 = fmaf(xx[p][k+2], w.z, a0); a0 = fmaf(xx[p][k+3], w.w, a0);
      a1 = fmaf(xx[p+1][k], w.x, a1); a1 = fmaf(xx[p+1][k+1], w.y, a1);
      a1 = fmaf(xx[p+1][k+2], w.z, a1); a1 = fmaf(xx[p+1][k+3], w.w, a1);
    }
    qout[(size_t)p * 384 + o] = a0;
    qout[(size_t)(p + 1) * 384 + o] = a1;
  }
}

// ================================================================
// K35 v2: e-slice attention, no max-subtraction (scores bounded, fp32-exp
// safe), K-split across blockIdx.z (partials additive since no max state).
// grid (48 l-tiles, 4 heads, 4 k-splits), 256 threads.
// Q in registers; K/V transposed [dim][col] stride 68 -> all b128 LDS reads.
// Writes partial numerator AOP[s] and denom DEN[s]; k7 combines.
// ================================================================
__global__ __launch_bounds__(256) void k35_flash_e(float* __restrict__ ws)
{
  __shared__ float Qs[16 * 36];
  __shared__ float KsT[32 * 68];
  __shared__ float VsT[32 * 68];
  __shared__ float Ss[16 * 68];
  const int t  = threadIdx.x;
  const int l0 = blockIdx.x * 16, h = blockIdx.y, sp = blockIdx.z;
  const float* qkve = ws + OFF_QKVE;

  for (int f = t; f < 512; f += 256)
    Qs[(f >> 5) * 36 + (f & 31)] = qkve[(size_t)(l0 + (f >> 5)) * 384 + h * 32 + (f & 31)];
  __syncthreads();

  const int l = t >> 4, j = t & 15, c0 = j * 4;
  float q[32];
  #pragma unroll
  for (int dd = 0; dd < 8; ++dd) {
    float4 qq = *(const float4*)&Qs[l * 36 + dd * 4];
    q[dd*4+0] = qq.x; q[dd*4+1] = qq.y; q[dd*4+2] = qq.z; q[dd*4+3] = qq.w;
  }
  float o0 = 0.f, o1 = 0.f, dsum = 0.f;

  for (int mt = sp * 3; mt < sp * 3 + 3; ++mt) {
    const int m0 = mt * 64;
    __syncthreads();   // previous tile's readers done before overwrite
    for (int f = t; f < 2048; f += 256) {
      int i = f >> 5, d = f & 31;
      const float* src = qkve + (size_t)(m0 + i) * 384 + h * 32 + d;
      KsT[d * 68 + i] = src[128];
      VsT[d * 68 + i] = src[256];
    }
    __syncthreads();

    float s0 = 0.f, s1 = 0.f, s2 = 0.f, s3 = 0.f;
    #pragma unroll
    for (int d = 0; d < 32; ++d) {
      float4 kk = *(const float4*)&KsT[d * 68 + c0];
      s0 = fmaf(q[d], kk.x, s0); s1 = fmaf(q[d], kk.y, s1);
      s2 = fmaf(q[d], kk.z, s2); s3 = fmaf(q[d], kk.w, s3);
    }
    s0 = expf(s0 * SCALE_ATTN); s1 = expf(s1 * SCALE_ATTN);
    s2 = expf(s2 * SCALE_ATTN); s3 = expf(s3 * SCALE_ATTN);
    float4 sv; sv.x = s0; sv.y = s1; sv.z = s2; sv.w = s3;
    *(float4*)&Ss[l * 68 + c0] = sv;   // row l owned by these 16 lanes (same wave)
    float psum = (s0 + s1) + (s2 + s3);
    psum += __shfl_xor(psum, 1); psum += __shfl_xor(psum, 2);
    psum += __shfl_xor(psum, 4); psum += __shfl_xor(psum, 8);
    dsum += psum;

    // PV: Ss row l read by the same wave that wrote it -> no block barrier
    #pragma unroll
    for (int k4 = 0; k4 < 16; ++k4) {
      float4 p  = *(const float4*)&Ss[l * 68 + k4 * 4];
      float4 va = *(const float4*)&VsT[j * 68 + k4 * 4];
      float4 vb = *(const float4*)&VsT[(j + 16) * 68 + k4 * 4];
      o0 = fmaf(p.x, va.x, o0); o0 = fmaf(p.y, va.y, o0);
      o0 = fmaf(p.z, va.z, o0); o0 = fmaf(p.w, va.w, o0);
      o1 = fmaf(p.x, vb.x, o1); o1 = fmaf(p.y, vb.y, o1);
      o1 = fmaf(p.z, vb.z, o1); o1 = fmaf(p.w, vb.w, o1);
    }
  }

  float* aop = ws + OFF_AOP + (size_t)sp * 98304;
  aop[(size_t)(l0 + l) * 128 + h * 32 + j]      = o0;
  aop[(size_t)(l0 + l) * 128 + h * 32 + j + 16] = o1;
  if (j == 0) ws[OFF_DEN + sp * 3072 + (l0 + l) * 4 + h] = dsum;
}

// ================================================================
// K6: slices j=1..15, dedup'd weighted softmax (no max-subtraction;
// serial softmax pass replaced by in-register exp + 16-lane butterfly).
// ================================================================
__global__ __launch_bounds__(256) void k6_a_slices(float* __restrict__ ws)
{
  __shared__ float Qb[48 * 33];
  __shared__ float Ka[96 * 33];
  __shared__ __align__(16) float Va[96 * 36];
  __shared__ float Ss[48 * 97];
  __shared__ float rinv[48];
  const int t  = threadIdx.x;
  const int z  = blockIdx.x;
  const int j1 = z >> 3;
  const int h  = (z & 7) >> 1, rb = z & 1;
  const int jj = j1 + 1;
  const float* qkva = ws + OFF_QKVA;

  for (int f = t; f < 3072; f += 256) {
    int ml = f >> 5, d = f & 31;
    int bp = ml >> 1, spar = ml & 1;
    int ag = spar ? jj : (jj - 1);
    const float* src = qkva + (size_t)(bp * 16 + ag) * 384 + h * 32 + d;
    Ka[ml * 33 + d] = src[128];
    Va[ml * 36 + d] = src[256];
  }
  for (int f = t; f < 1536; f += 256) {
    int ql = f >> 5, d = f & 31;
    int Lb = rb * 48 + ql;
    int b = Lb >> 1, s = Lb & 1;
    int ag = s ? jj : (jj - 1);
    Qb[ql * 33 + d] = qkva[(size_t)(b * 16 + ag) * 384 + h * 32 + d];
  }
  __syncthreads();

  { // scores 48x96 -> weighted exp in-register -> Ss + row sums
    const int tl = (t >> 4) * 3, tm = (t & 15) * 6;
    float acc[3][6] = {{0.f}};
    #pragma unroll
    for (int d = 0; d < 32; ++d) {
      float qv[3], kv[6];
      #pragma unroll
      for (int r = 0; r < 3; ++r) qv[r] = Qb[(tl + r) * 33 + d];
      #pragma unroll
      for (int c = 0; c < 6; ++c) kv[c] = Ka[(tm + c) * 33 + d];
      #pragma unroll
      for (int r = 0; r < 3; ++r)
        #pragma unroll
        for (int c = 0; c < 6; ++c) acc[r][c] = fmaf(qv[r], kv[c], acc[r][c]);
    }
    const float wj = (float)jj, wnj = (float)(16 - jj);
    float rs[3] = {0.f, 0.f, 0.f};
    #pragma unroll
    for (int r = 0; r < 3; ++r)
      #pragma unroll
      for (int c = 0; c < 6; ++c) {
        float w = ((tm + c) & 1) ? wj : wnj;
        float p = w * expf(acc[r][c] * SCALE_ATTN);
        Ss[(tl + r) * 97 + tm + c] = p;
        rs[r] += p;
      }
    #pragma unroll
    for (int r = 0; r < 3; ++r) {
      rs[r] += __shfl_xor(rs[r], 1); rs[r] += __shfl_xor(rs[r], 2);
      rs[r] += __shfl_xor(rs[r], 4); rs[r] += __shfl_xor(rs[r], 8);
    }
    if ((t & 15) == 0) {
      rinv[tl + 0] = 1.f / rs[0];
      rinv[tl + 1] = 1.f / rs[1];
      rinv[tl + 2] = 1.f / rs[2];
    }
  }
  __syncthreads();

  if (t < 192) { // P@V
    const int l0 = (t >> 3) * 2, d0 = (t & 7) * 4;
    float a0x=0.f,a0y=0.f,a0z=0.f,a0w=0.f, a1x=0.f,a1y=0.f,a1z=0.f,a1w=0.f;
    for (int m = 0; m < 96; ++m) {
      float p0 = Ss[l0 * 97 + m], p1 = Ss[(l0 + 1) * 97 + m];
      float4 v = *(const float4*)&Va[m * 36 + d0];
      a0x = fmaf(p0, v.x, a0x); a0y = fmaf(p0, v.y, a0y);
      a0z = fmaf(p0, v.z, a0z); a0w = fmaf(p0, v.w, a0w);
      a1x = fmaf(p1, v.x, a1x); a1y = fmaf(p1, v.y, a1y);
      a1z = fmaf(p1, v.z, a1z); a1w = fmaf(p1, v.w, a1w);
    }
    const float s0 = rinv[l0], s1 = rinv[l0 + 1];
    float* ao = ws + OFF_AOA + (size_t)(j1 * 96 + rb * 48 + l0) * 128 + h * 32 + d0;
    float4 o0; o0.x = a0x * s0; o0.y = a0y * s0; o0.z = a0z * s0; o0.w = a0w * s0;
    float4 o1; o1.x = a1x * s1; o1.y = a1y * s1; o1.z = a1z * s1; o1.w = a1w * s1;
    *(float4*)ao = o0;
    *(float4*)(ao + 128) = o1;
  }
}

// ================================================================
// K7: epilogue per distinct ctx row (2208 rows), 4/block. grid=552.
// For e-rows (r<768): combine the 4 k-split partials (sum num / sum den).
// Blocks are homogeneous (768 = 192*4, no mixed block).
// ================================================================
__global__ __launch_bounds__(128) void k7_epilogue(
    const float* __restrict__ mow, const float* __restrict__ mob,
    const float* __restrict__ roww, const float* __restrict__ robb,
    const float* __restrict__ qw,  const float* __restrict__ qb,
    float* __restrict__ ws)
{
  __shared__ float ao_s[4][128];
  __shared__ float t1[4][128];
  __shared__ float red2[4][2];
  const int t  = threadIdx.x;
  const int r0 = blockIdx.x * 4;

  if (r0 < 768) { // e-rows: combine partials
    for (int f = t; f < 512; f += 128) {
      int i = f >> 7, c = f & 127;
      int r = r0 + i, h = c >> 5;
      float num = ws[OFF_AOP + 0*98304 + (size_t)r*128 + c]
                + ws[OFF_AOP + 1*98304 + (size_t)r*128 + c]
                + ws[OFF_AOP + 2*98304 + (size_t)r*128 + c]
                + ws[OFF_AOP + 3*98304 + (size_t)r*128 + c];
      float den = ws[OFF_DEN + 0*3072 + r*4 + h]
                + ws[OFF_DEN + 1*3072 + r*4 + h]
                + ws[OFF_DEN + 2*3072 + r*4 + h]
                + ws[OFF_DEN + 3*3072 + r*4 + h];
      ao_s[i][c] = num / den;
    }
  } else {
    for (int f = t; f < 512; f += 128) {
      int i = f >> 7, c = f & 127;
      ao_s[i][c] = ws[OFF_AOA + (size_t)(r0 + i - 768) * 128 + c];
    }
  }

  int x1off[4];
  #pragma unroll
  for (int i = 0; i < 4; ++i) {
    int r = r0 + i;
    if (r < 768) x1off[i] = OFF_XE + r * 128;
    else {
      int rr = r - 768;
      int jx = rr / 96, l96 = rr % 96;
      int b = l96 >> 1, s = l96 & 1;
      int ag = s ? (jx + 1) : jx;
      x1off[i] = OFF_XA + (b * 16 + ag) * 128;
    }
  }
  __syncthreads();

  { // out_proj + residual
    const int o = t;
    const float bo = mob[o];
    float acc[4] = {bo, bo, bo, bo};
    const float4* wr = (const float4*)(mow + o * 128);
    #pragma unroll 8
    for (int kk = 0; kk < 32; ++kk) {
      float4 w = wr[kk];
      const int k = kk * 4;
      #pragma unroll
      for (int i = 0; i < 4; ++i) {
        acc[i] = fmaf(ao_s[i][k], w.x, acc[i]); acc[i] = fmaf(ao_s[i][k+1], w.y, acc[i]);
        acc[i] = fmaf(ao_s[i][k+2], w.z, acc[i]); acc[i] = fmaf(ao_s[i][k+3], w.w, acc[i]);
      }
    }
    #pragma unroll
    for (int i = 0; i < 4; ++i) t1[i][o] = acc[i] + ws[x1off[i] + o];
  }
  __syncthreads();

  float c4[4];
  { // ctx = relu(row @ t1 + rob)
    const int o = t;
    const float bo = robb[o];
    float acc[4] = {bo, bo, bo, bo};
    const float4* wr = (const float4*)(roww + o * 128);
    #pragma unroll 8
    for (int kk = 0; kk < 32; ++kk) {
      float4 w = wr[kk];
      const int k = kk * 4;
      #pragma unroll
      for (int i = 0; i < 4; ++i) {
        acc[i] = fmaf(t1[i][k], w.x, acc[i]); acc[i] = fmaf(t1[i][k+1], w.y, acc[i]);
        acc[i] = fmaf(t1[i][k+2], w.z, acc[i]); acc[i] = fmaf(t1[i][k+3], w.w, acc[i]);
      }
    }
    #pragma unroll
    for (int i = 0; i < 4; ++i) c4[i] = fmaxf(acc[i], 0.f);
  }

  const float qwt = qw[t];
  #pragma unroll
  for (int i = 0; i < 4; ++i) {
    float v = qwt * c4[i];
    v += __shfl_down(v, 32); v += __shfl_down(v, 16); v += __shfl_down(v, 8);
    v += __shfl_down(v, 4);  v += __shfl_down(v, 2);  v += __shfl_down(v, 1);
    if ((t & 63) == 0) red2[i][t >> 6] = v;
  }
  __syncthreads();
  if (t < 4) {
    float qv = red2[t][0] + red2[t][1] + qb[0];
    int r = r0 + t;
    if (r < 768) ws[OFF_QVE + r] = qv;
    else         ws[OFF_QVA + (r - 768)] = qv;
  }
}

// ================================================================
// K8: q_values[b,i] = qv_e[b,i] + sum_j qv_a
// ================================================================
__global__ __launch_bounds__(256) void k8_final(const float* __restrict__ ws, float* __restrict__ out)
{
  const int idx = blockIdx.x * 256 + threadIdx.x;
  if (idx >= 768) return;
  const int b = idx >> 4, i = idx & 15;
  float acc = ws[OFF_QVE + idx];
  const float* qva = ws + OFF_QVA;
  #pragma unroll
  for (int j = 1; j <= 15; ++j) {
    int s = (i >= j) ? 0 : 1;
    acc += qva[(j - 1) * 96 + b * 2 + s];
  }
  out[OUT_QV + idx] = acc;
}

// ================================================================
extern "C" void kernel_launch(void* const* d_in, const int* in_sizes, int n_in,
                              void* d_out, int out_size, void* d_ws, size_t ws_size,
                              hipStream_t stream)
{
  (void)in_sizes; (void)n_in; (void)out_size;
  if (ws_size < (size_t)WS_FLOATS * 4) return;

  const float* obs = (const float*)d_in[0];
  const float* aw1 = (const float*)d_in[1];
  const float* ab1 = (const float*)d_in[2];
  const float* aw2 = (const float*)d_in[3];
  const float* ab2 = (const float*)d_in[4];
  const float* aw3 = (const float*)d_in[5];
  const float* ab3 = (const float*)d_in[6];
  const float* eow = (const float*)d_in[7];
  const float* eob = (const float*)d_in[8];
  const float* eaw = (const float*)d_in[9];
  const float* eab = (const float*)d_in[10];
  const float* riw = (const float*)d_in[11];
  const float* rib = (const float*)d_in[12];
  const float* roww= (const float*)d_in[13];
  const float* robb= (const float*)d_in[14];
  const float* miw = (const float*)d_in[15];
  const float* mib = (const float*)d_in[16];
  const float* mow = (const float*)d_in[17];
  const float* mob = (const float*)d_in[18];
  const float* qw  = (const float*)d_in[19];
  const float* qb  = (const float*)d_in[20];

  float* out = (float*)d_out;
  float* ws  = (float*)d_ws;

  k1_actor_enc<<<dim3(384), dim3(256), 0, stream>>>(obs, aw1, ab1, aw2, ab2, aw3, ab3,
                                                    eow, eob, eaw, eab, out, ws);
  k2_rsa_in<<<dim3(384), dim3(256), 0, stream>>>(riw, rib, miw, mib, ws);
  k35_flash_e<<<dim3(48, 4, 4), dim3(256), 0, stream>>>(ws);
  k6_a_slices<<<dim3(120), dim3(256), 0, stream>>>(ws);
  k7_epilogue<<<dim3(552), dim3(128), 0, stream>>>(mow, mob, roww, robb, qw, qb, ws);
  k8_final<<<dim3(3), dim3(256), 0, stream>>>(ws, out);
}

// Round 8
// 197.935 us; speedup vs baseline: 1.2426x; 1.0078x over previous
//
#include <hip/hip_runtime.h>
#include <math.h>

static __device__ __forceinline__ float lrelu(float x){ return x > 0.f ? x : 0.01f * x; }

// ---- workspace layout (float offsets) ----
#define OFF_XE    196608    // 768*128
#define OFF_XA    294912    // 768*128
#define OFF_QKVE  393216    // 768*384
#define OFF_QKVA  688128    // 768*384
#define OFF_AOP   983040    // 4 splits * 768*128 (e partial O numerator)
#define OFF_DEN   1376256   // 4 splits * 768*4 (e partial denom)
#define OFF_AOA   1388544   // 15*96*128
#define OFF_QVE   1572864   // 768
#define OFF_QVA   1573632   // 15*96 (pad)
#define WS_FLOATS 1575072   // ~6.3 MB

// ---- output layout (fp32 elems) ----
#define OUT_POL 0
#define OUT_QV  24576
#define OUT_EO  25344

#define SCALE_ATTN 0.17677669529663689f  // 1/sqrt(32)

// ================================================================
// K12: actor + encoders + RSA input + QKV, fully fused per 2 rows.
// grid=384, 256 threads. All LDS reads are b128.
// ================================================================
__global__ __launch_bounds__(256) void k12_front(
    const float* __restrict__ obs,
    const float* __restrict__ aw1, const float* __restrict__ ab1,
    const float* __restrict__ aw2, const float* __restrict__ ab2,
    const float* __restrict__ aw3, const float* __restrict__ ab3,
    const float* __restrict__ eow, const float* __restrict__ eob,
    const float* __restrict__ eaw, const float* __restrict__ eab,
    const float* __restrict__ riw, const float* __restrict__ rib,
    const float* __restrict__ miw, const float* __restrict__ mib,
    float* __restrict__ out, float* __restrict__ ws)
{
  __shared__ float obs_s[2][128];
  __shared__ float h1[2][256];
  __shared__ float h2[2][128];
  __shared__ float pol[2][32];
  __shared__ float eo_s[2][128];
  __shared__ float ea_s[2][128];
  __shared__ float xx[2][2][128];   // [variant e/a][row][col]
  const int t  = threadIdx.x;
  const int r0 = blockIdx.x * 2;

  { int r = t >> 7, k = t & 127;
    obs_s[r][k] = obs[(r0 + r) * 128 + k]; }
  __syncthreads();

  { // layer1: 256 outputs x 2 rows
    const int o = t;
    float a0 = ab1[o]; float a1 = a0;
    const float4* wr = (const float4*)(aw1 + o * 128);
    #pragma unroll 8
    for (int kk = 0; kk < 32; ++kk) {
      float4 w  = wr[kk];
      float4 x0 = *(const float4*)&obs_s[0][kk * 4];
      float4 x1 = *(const float4*)&obs_s[1][kk * 4];
      a0 = fmaf(x0.x, w.x, a0); a0 = fmaf(x0.y, w.y, a0);
      a0 = fmaf(x0.z, w.z, a0); a0 = fmaf(x0.w, w.w, a0);
      a1 = fmaf(x1.x, w.x, a1); a1 = fmaf(x1.y, w.y, a1);
      a1 = fmaf(x1.z, w.z, a1); a1 = fmaf(x1.w, w.w, a1);
    }
    h1[0][o] = lrelu(a0); h1[1][o] = lrelu(a1);
  }
  __syncthreads();

  if (t < 128) { // layer2
    const int o = t;
    float a0 = ab2[o]; float a1 = a0;
    const float4* wr = (const float4*)(aw2 + o * 256);
    #pragma unroll 8
    for (int kk = 0; kk < 64; ++kk) {
      float4 w  = wr[kk];
      float4 x0 = *(const float4*)&h1[0][kk * 4];
      float4 x1 = *(const float4*)&h1[1][kk * 4];
      a0 = fmaf(x0.x, w.x, a0); a0 = fmaf(x0.y, w.y, a0);
      a0 = fmaf(x0.z, w.z, a0); a0 = fmaf(x0.w, w.w, a0);
      a1 = fmaf(x1.x, w.x, a1); a1 = fmaf(x1.y, w.y, a1);
      a1 = fmaf(x1.z, w.z, a1); a1 = fmaf(x1.w, w.w, a1);
    }
    h2[0][o] = lrelu(a0); h2[1][o] = lrelu(a1);
  }
  __syncthreads();

  if (t < 64) { // layer3 + exact GELU -> policy
    const int o = t & 31, r = t >> 5;
    float a = ab3[o];
    const float4* wr = (const float4*)(aw3 + o * 128);
    #pragma unroll 8
    for (int kk = 0; kk < 32; ++kk) {
      float4 w = wr[kk];
      float4 x = *(const float4*)&h2[r][kk * 4];
      a = fmaf(x.x, w.x, a); a = fmaf(x.y, w.y, a);
      a = fmaf(x.z, w.z, a); a = fmaf(x.w, w.w, a);
    }
    float g = 0.5f * a * (1.f + erff(a * 0.70710678118654752f));
    pol[r][o] = g;
    out[OUT_POL + (r0 + r) * 32 + o] = g;
  }
  __syncthreads();

  if (t < 128) { // eo = obs @ eow^T + eob
    const int o = t;
    float a0 = eob[o]; float a1 = a0;
    const float4* wr = (const float4*)(eow + o * 128);
    #pragma unroll 8
    for (int kk = 0; kk < 32; ++kk) {
      float4 w  = wr[kk];
      float4 x0 = *(const float4*)&obs_s[0][kk * 4];
      float4 x1 = *(const float4*)&obs_s[1][kk * 4];
      a0 = fmaf(x0.x, w.x, a0); a0 = fmaf(x0.y, w.y, a0);
      a0 = fmaf(x0.z, w.z, a0); a0 = fmaf(x0.w, w.w, a0);
      a1 = fmaf(x1.x, w.x, a1); a1 = fmaf(x1.y, w.y, a1);
      a1 = fmaf(x1.z, w.z, a1); a1 = fmaf(x1.w, w.w, a1);
    }
    eo_s[0][o] = a0; eo_s[1][o] = a1;
    out[OUT_EO + (r0 + 0) * 128 + o] = a0;
    out[OUT_EO + (r0 + 1) * 128 + o] = a1;
  } else {       // ea = [obs, policy] @ eaw^T + eab
    const int o = t - 128;
    float a0 = eab[o]; float a1 = a0;
    const float4* wr = (const float4*)(eaw + o * 160);  // 40 float4
    #pragma unroll 8
    for (int kk = 0; kk < 32; ++kk) {
      float4 w  = wr[kk];
      float4 x0 = *(const float4*)&obs_s[0][kk * 4];
      float4 x1 = *(const float4*)&obs_s[1][kk * 4];
      a0 = fmaf(x0.x, w.x, a0); a0 = fmaf(x0.y, w.y, a0);
      a0 = fmaf(x0.z, w.z, a0); a0 = fmaf(x0.w, w.w, a0);
      a1 = fmaf(x1.x, w.x, a1); a1 = fmaf(x1.y, w.y, a1);
      a1 = fmaf(x1.z, w.z, a1); a1 = fmaf(x1.w, w.w, a1);
    }
    #pragma unroll
    for (int kk = 32; kk < 40; ++kk) {
      float4 w  = wr[kk];
      float4 p0 = *(const float4*)&pol[0][kk * 4 - 128];
      float4 p1 = *(const float4*)&pol[1][kk * 4 - 128];
      a0 = fmaf(p0.x, w.x, a0); a0 = fmaf(p0.y, w.y, a0);
      a0 = fmaf(p0.z, w.z, a0); a0 = fmaf(p0.w, w.w, a0);
      a1 = fmaf(p1.x, w.x, a1); a1 = fmaf(p1.y, w.y, a1);
      a1 = fmaf(p1.z, w.z, a1); a1 = fmaf(p1.w, w.w, a1);
    }
    ea_s[0][o] = a0; ea_s[1][o] = a1;
  }
  __syncthreads();

  { // X phase: x_{e|a}[row] = relu(riw @ {eo|ea}[row] + rib)
    const int o = t & 127, v = t >> 7;
    const float (*src)[128] = v ? ea_s : eo_s;
    float a0 = rib[o]; float a1 = a0;
    const float4* wr = (const float4*)(riw + o * 128);
    #pragma unroll 8
    for (int kk = 0; kk < 32; ++kk) {
      float4 w  = wr[kk];
      float4 x0 = *(const float4*)&src[0][kk * 4];
      float4 x1 = *(const float4*)&src[1][kk * 4];
      a0 = fmaf(x0.x, w.x, a0); a0 = fmaf(x0.y, w.y, a0);
      a0 = fmaf(x0.z, w.z, a0); a0 = fmaf(x0.w, w.w, a0);
      a1 = fmaf(x1.x, w.x, a1); a1 = fmaf(x1.y, w.y, a1);
      a1 = fmaf(x1.z, w.z, a1); a1 = fmaf(x1.w, w.w, a1);
    }
    a0 = fmaxf(a0, 0.f); a1 = fmaxf(a1, 0.f);
    xx[v][0][o] = a0; xx[v][1][o] = a1;
    float* xout = ws + (v ? OFF_XA : OFF_XE) + r0 * 128;
    xout[o] = a0; xout[128 + o] = a1;
  }
  __syncthreads();

  { // QKV phase: qkv_{e|a} = miw @ x + mib (384 outputs x 2 rows x 2 variants)
    const int o128 = t & 127, v = t >> 7;
    float* qout = ws + (v ? OFF_QKVA : OFF_QKVE) + (size_t)r0 * 384;
    #pragma unroll
    for (int p3 = 0; p3 < 3; ++p3) {
      const int o = p3 * 128 + o128;
      float a0 = mib[o]; float a1 = a0;
      const float4* wr = (const float4*)(miw + o * 128);
      #pragma unroll 8
      for (int kk = 0; kk < 32; ++kk) {
        float4 w  = wr[kk];
        float4 x0 = *(const float4*)&xx[v][0][kk * 4];
        float4 x1 = *(const float4*)&xx[v][1][kk * 4];
        a0 = fmaf(x0.x, w.x, a0); a0 = fmaf(x0.y, w.y, a0);
        a0 = fmaf(x0.z, w.z, a0); a0 = fmaf(x0.w, w.w, a0);
        a1 = fmaf(x1.x, w.x, a1); a1 = fmaf(x1.y, w.y, a1);
        a1 = fmaf(x1.z, w.z, a1); a1 = fmaf(x1.w, w.w, a1);
      }
      qout[o] = a0; qout[384 + o] = a1;
    }
  }
}

// ================================================================
// K356: fused attention. Blocks 0..767: e-slice flash (l-tile, head,
// k-split); blocks 768..887: a-slices j=1..15. LDS is a union.
// ================================================================
__global__ __launch_bounds__(256) void k356_attn(float* __restrict__ ws)
{
  __shared__ __align__(16) union {
    struct { float Qs[16 * 36]; float KsT[32 * 68]; float VsT[32 * 68]; float Ss[16 * 68]; } e;
    struct { float Qb[48 * 33]; float Ka[96 * 33]; float Va[96 * 36]; float Ss[48 * 97]; float rinv[48]; } a;
  } su;
  const int t  = threadIdx.x;
  const int bx = blockIdx.x;

  if (bx < 768) {
    // ---------------- e-slice flash ----------------
    const int l0 = (bx % 48) * 16, h = (bx / 48) & 3, sp = bx / 192;
    const float* qkve = ws + OFF_QKVE;

    for (int f = t; f < 512; f += 256)
      su.e.Qs[(f >> 5) * 36 + (f & 31)] = qkve[(size_t)(l0 + (f >> 5)) * 384 + h * 32 + (f & 31)];
    __syncthreads();

    const int l = t >> 4, j = t & 15, c0 = j * 4;
    float q[32];
    #pragma unroll
    for (int dd = 0; dd < 8; ++dd) {
      float4 qq = *(const float4*)&su.e.Qs[l * 36 + dd * 4];
      q[dd*4+0] = qq.x; q[dd*4+1] = qq.y; q[dd*4+2] = qq.z; q[dd*4+3] = qq.w;
    }
    float o0 = 0.f, o1 = 0.f, dsum = 0.f;

    for (int mt = sp * 3; mt < sp * 3 + 3; ++mt) {
      const int m0 = mt * 64;
      __syncthreads();
      for (int f = t; f < 2048; f += 256) {
        int i = f >> 5, d = f & 31;
        const float* src = qkve + (size_t)(m0 + i) * 384 + h * 32 + d;
        su.e.KsT[d * 68 + i] = src[128];
        su.e.VsT[d * 68 + i] = src[256];
      }
      __syncthreads();

      float s0 = 0.f, s1 = 0.f, s2 = 0.f, s3 = 0.f;
      #pragma unroll
      for (int d = 0; d < 32; ++d) {
        float4 kk = *(const float4*)&su.e.KsT[d * 68 + c0];
        s0 = fmaf(q[d], kk.x, s0); s1 = fmaf(q[d], kk.y, s1);
        s2 = fmaf(q[d], kk.z, s2); s3 = fmaf(q[d], kk.w, s3);
      }
      s0 = expf(s0 * SCALE_ATTN); s1 = expf(s1 * SCALE_ATTN);
      s2 = expf(s2 * SCALE_ATTN); s3 = expf(s3 * SCALE_ATTN);
      float4 sv; sv.x = s0; sv.y = s1; sv.z = s2; sv.w = s3;
      *(float4*)&su.e.Ss[l * 68 + c0] = sv;
      float psum = (s0 + s1) + (s2 + s3);
      psum += __shfl_xor(psum, 1); psum += __shfl_xor(psum, 2);
      psum += __shfl_xor(psum, 4); psum += __shfl_xor(psum, 8);
      dsum += psum;

      #pragma unroll
      for (int k4 = 0; k4 < 16; ++k4) {
        float4 p  = *(const float4*)&su.e.Ss[l * 68 + k4 * 4];
        float4 va = *(const float4*)&su.e.VsT[j * 68 + k4 * 4];
        float4 vb = *(const float4*)&su.e.VsT[(j + 16) * 68 + k4 * 4];
        o0 = fmaf(p.x, va.x, o0); o0 = fmaf(p.y, va.y, o0);
        o0 = fmaf(p.z, va.z, o0); o0 = fmaf(p.w, va.w, o0);
        o1 = fmaf(p.x, vb.x, o1); o1 = fmaf(p.y, vb.y, o1);
        o1 = fmaf(p.z, vb.z, o1); o1 = fmaf(p.w, vb.w, o1);
      }
    }

    float* aop = ws + OFF_AOP + (size_t)sp * 98304;
    aop[(size_t)(l0 + l) * 128 + h * 32 + j]      = o0;
    aop[(size_t)(l0 + l) * 128 + h * 32 + j + 16] = o1;
    if (j == 0) ws[OFF_DEN + sp * 3072 + (l0 + l) * 4 + h] = dsum;
  } else {
    // ---------------- a-slices ----------------
    const int z  = bx - 768;
    const int j1 = z >> 3;
    const int h  = (z & 7) >> 1, rb = z & 1;
    const int jj = j1 + 1;
    const float* qkva = ws + OFF_QKVA;

    for (int f = t; f < 3072; f += 256) {
      int ml = f >> 5, d = f & 31;
      int bp = ml >> 1, spar = ml & 1;
      int ag = spar ? jj : (jj - 1);
      const float* src = qkva + (size_t)(bp * 16 + ag) * 384 + h * 32 + d;
      su.a.Ka[ml * 33 + d] = src[128];
      su.a.Va[ml * 36 + d] = src[256];
    }
    for (int f = t; f < 1536; f += 256) {
      int ql = f >> 5, d = f & 31;
      int Lb = rb * 48 + ql;
      int b = Lb >> 1, s = Lb & 1;
      int ag = s ? jj : (jj - 1);
      su.a.Qb[ql * 33 + d] = qkva[(size_t)(b * 16 + ag) * 384 + h * 32 + d];
    }
    __syncthreads();

    { // scores 48x96 -> weighted exp -> Ss + row sums
      const int tl = (t >> 4) * 3, tm = (t & 15) * 6;
      float acc[3][6] = {{0.f}};
      #pragma unroll
      for (int d = 0; d < 32; ++d) {
        float qv[3], kv[6];
        #pragma unroll
        for (int r = 0; r < 3; ++r) qv[r] = su.a.Qb[(tl + r) * 33 + d];
        #pragma unroll
        for (int c = 0; c < 6; ++c) kv[c] = su.a.Ka[(tm + c) * 33 + d];
        #pragma unroll
        for (int r = 0; r < 3; ++r)
          #pragma unroll
          for (int c = 0; c < 6; ++c) acc[r][c] = fmaf(qv[r], kv[c], acc[r][c]);
      }
      const float wj = (float)jj, wnj = (float)(16 - jj);
      float rs[3] = {0.f, 0.f, 0.f};
      #pragma unroll
      for (int r = 0; r < 3; ++r)
        #pragma unroll
        for (int c = 0; c < 6; ++c) {
          float w = ((tm + c) & 1) ? wj : wnj;
          float p = w * expf(acc[r][c] * SCALE_ATTN);
          su.a.Ss[(tl + r) * 97 + tm + c] = p;
          rs[r] += p;
        }
      #pragma unroll
      for (int r = 0; r < 3; ++r) {
        rs[r] += __shfl_xor(rs[r], 1); rs[r] += __shfl_xor(rs[r], 2);
        rs[r] += __shfl_xor(rs[r], 4); rs[r] += __shfl_xor(rs[r], 8);
      }
      if ((t & 15) == 0) {
        su.a.rinv[tl + 0] = 1.f / rs[0];
        su.a.rinv[tl + 1] = 1.f / rs[1];
        su.a.rinv[tl + 2] = 1.f / rs[2];
      }
    }
    __syncthreads();

    if (t < 192) { // P@V
      const int l0 = (t >> 3) * 2, d0 = (t & 7) * 4;
      float a0x=0.f,a0y=0.f,a0z=0.f,a0w=0.f, a1x=0.f,a1y=0.f,a1z=0.f,a1w=0.f;
      for (int m = 0; m < 96; ++m) {
        float p0 = su.a.Ss[l0 * 97 + m], p1 = su.a.Ss[(l0 + 1) * 97 + m];
        float4 v = *(const float4*)&su.a.Va[m * 36 + d0];
        a0x = fmaf(p0, v.x, a0x); a0y = fmaf(p0, v.y, a0y);
        a0z = fmaf(p0, v.z, a0z); a0w = fmaf(p0, v.w, a0w);
        a1x = fmaf(p1, v.x, a1x); a1y = fmaf(p1, v.y, a1y);
        a1z = fmaf(p1, v.z, a1z); a1w = fmaf(p1, v.w, a1w);
      }
      const float s0 = su.a.rinv[l0], s1 = su.a.rinv[l0 + 1];
      float* ao = ws + OFF_AOA + (size_t)(j1 * 96 + rb * 48 + l0) * 128 + h * 32 + d0;
      float4 o0; o0.x = a0x * s0; o0.y = a0y * s0; o0.z = a0z * s0; o0.w = a0w * s0;
      float4 o1; o1.x = a1x * s1; o1.y = a1y * s1; o1.z = a1z * s1; o1.w = a1w * s1;
      *(float4*)ao = o0;
      *(float4*)(ao + 128) = o1;
    }
  }
}

// ================================================================
// K7: epilogue, 2 ctx rows per 128-thread block. grid=1104
// (blocks 0..383: e-rows with k-split combine; 384..1103: a-rows).
// ================================================================
__global__ __launch_bounds__(128) void k7_epilogue(
    const float* __restrict__ mow, const float* __restrict__ mob,
    const float* __restrict__ roww, const float* __restrict__ robb,
    const float* __restrict__ qw,  const float* __restrict__ qb,
    float* __restrict__ ws)
{
  __shared__ float ao_s[2][128];
  __shared__ float t1[2][128];
  __shared__ float red2[2][2];
  const int t  = threadIdx.x;
  const int bx = blockIdx.x;
  const bool is_e = (bx < 384);
  const int r0 = is_e ? bx * 2 : (bx - 384) * 2;   // e-row or a-row base

  int x1off[2];
  if (is_e) {
    for (int f = t; f < 256; f += 128) {
      int i = f >> 7, c = f & 127;
      int r = r0 + i, h = c >> 5;
      float num = ws[OFF_AOP + 0*98304 + (size_t)r*128 + c]
                + ws[OFF_AOP + 1*98304 + (size_t)r*128 + c]
                + ws[OFF_AOP + 2*98304 + (size_t)r*128 + c]
                + ws[OFF_AOP + 3*98304 + (size_t)r*128 + c];
      float den = ws[OFF_DEN + 0*3072 + r*4 + h]
                + ws[OFF_DEN + 1*3072 + r*4 + h]
                + ws[OFF_DEN + 2*3072 + r*4 + h]
                + ws[OFF_DEN + 3*3072 + r*4 + h];
      ao_s[i][c] = num / den;
    }
    x1off[0] = OFF_XE + r0 * 128;
    x1off[1] = OFF_XE + (r0 + 1) * 128;
  } else {
    for (int f = t; f < 256; f += 128) {
      int i = f >> 7, c = f & 127;
      ao_s[i][c] = ws[OFF_AOA + (size_t)(r0 + i) * 128 + c];
    }
    #pragma unroll
    for (int i = 0; i < 2; ++i) {
      int rr = r0 + i;
      int jx = rr / 96, l96 = rr % 96;
      int b = l96 >> 1, s = l96 & 1;
      int ag = s ? (jx + 1) : jx;
      x1off[i] = OFF_XA + (b * 16 + ag) * 128;
    }
  }
  __syncthreads();

  { // out_proj + residual
    const int o = t;
    const float bo = mob[o];
    float acc0 = bo, acc1 = bo;
    const float4* wr = (const float4*)(mow + o * 128);
    #pragma unroll 8
    for (int kk = 0; kk < 32; ++kk) {
      float4 w  = wr[kk];
      float4 x0 = *(const float4*)&ao_s[0][kk * 4];
      float4 x1 = *(const float4*)&ao_s[1][kk * 4];
      acc0 = fmaf(x0.x, w.x, acc0); acc0 = fmaf(x0.y, w.y, acc0);
      acc0 = fmaf(x0.z, w.z, acc0); acc0 = fmaf(x0.w, w.w, acc0);
      acc1 = fmaf(x1.x, w.x, acc1); acc1 = fmaf(x1.y, w.y, acc1);
      acc1 = fmaf(x1.z, w.z, acc1); acc1 = fmaf(x1.w, w.w, acc1);
    }
    t1[0][o] = acc0 + ws[x1off[0] + o];
    t1[1][o] = acc1 + ws[x1off[1] + o];
  }
  __syncthreads();

  float c0, c1;
  { // ctx = relu(row @ t1 + rob)
    const int o = t;
    const float bo = robb[o];
    float acc0 = bo, acc1 = bo;
    const float4* wr = (const float4*)(roww + o * 128);
    #pragma unroll 8
    for (int kk = 0; kk < 32; ++kk) {
      float4 w  = wr[kk];
      float4 x0 = *(const float4*)&t1[0][kk * 4];
      float4 x1 = *(const float4*)&t1[1][kk * 4];
      acc0 = fmaf(x0.x, w.x, acc0); acc0 = fmaf(x0.y, w.y, acc0);
      acc0 = fmaf(x0.z, w.z, acc0); acc0 = fmaf(x0.w, w.w, acc0);
      acc1 = fmaf(x1.x, w.x, acc1); acc1 = fmaf(x1.y, w.y, acc1);
      acc1 = fmaf(x1.z, w.z, acc1); acc1 = fmaf(x1.w, w.w, acc1);
    }
    c0 = fmaxf(acc0, 0.f); c1 = fmaxf(acc1, 0.f);
  }

  const float qwt = qw[t];
  {
    float v = qwt * c0;
    v += __shfl_down(v, 32); v += __shfl_down(v, 16); v += __shfl_down(v, 8);
    v += __shfl_down(v, 4);  v += __shfl_down(v, 2);  v += __shfl_down(v, 1);
    if ((t & 63) == 0) red2[0][t >> 6] = v;
    float u = qwt * c1;
    u += __shfl_down(u, 32); u += __shfl_down(u, 16); u += __shfl_down(u, 8);
    u += __shfl_down(u, 4);  u += __shfl_down(u, 2);  u += __shfl_down(u, 1);
    if ((t & 63) == 0) red2[1][t >> 6] = u;
  }
  __syncthreads();
  if (t < 2) {
    float qv = red2[t][0] + red2[t][1] + qb[0];
    int r = r0 + t;
    if (is_e) ws[OFF_QVE + r] = qv;
    else      ws[OFF_QVA + r] = qv;
  }
}

// ================================================================
// K8: q_values[b,i] = qv_e[b,i] + sum_j qv_a
// ================================================================
__global__ __launch_bounds__(256) void k8_final(const float* __restrict__ ws, float* __restrict__ out)
{
  const int idx = blockIdx.x * 256 + threadIdx.x;
  if (idx >= 768) return;
  const int b = idx >> 4, i = idx & 15;
  float acc = ws[OFF_QVE + idx];
  const float* qva = ws + OFF_QVA;
  #pragma unroll
  for (int j = 1; j <= 15; ++j) {
    int s = (i >= j) ? 0 : 1;
    acc += qva[(j - 1) * 96 + b * 2 + s];
  }
  out[OUT_QV + idx] = acc;
}

// ================================================================
extern "C" void kernel_launch(void* const* d_in, const int* in_sizes, int n_in,
                              void* d_out, int out_size, void* d_ws, size_t ws_size,
                              hipStream_t stream)
{
  (void)in_sizes; (void)n_in; (void)out_size;
  if (ws_size < (size_t)WS_FLOATS * 4) return;

  const float* obs = (const float*)d_in[0];
  const float* aw1 = (const float*)d_in[1];
  const float* ab1 = (const float*)d_in[2];
  const float* aw2 = (const float*)d_in[3];
  const float* ab2 = (const float*)d_in[4];
  const float* aw3 = (const float*)d_in[5];
  const float* ab3 = (const float*)d_in[6];
  const float* eow = (const float*)d_in[7];
  const float* eob = (const float*)d_in[8];
  const float* eaw = (const float*)d_in[9];
  const float* eab = (const float*)d_in[10];
  const float* riw = (const float*)d_in[11];
  const float* rib = (const float*)d_in[12];
  const float* roww= (const float*)d_in[13];
  const float* robb= (const float*)d_in[14];
  const float* miw = (const float*)d_in[15];
  const float* mib = (const float*)d_in[16];
  const float* mow = (const float*)d_in[17];
  const float* mob = (const float*)d_in[18];
  const float* qw  = (const float*)d_in[19];
  const float* qb  = (const float*)d_in[20];

  float* out = (float*)d_out;
  float* ws  = (float*)d_ws;

  k12_front<<<dim3(384), dim3(256), 0, stream>>>(obs, aw1, ab1, aw2, ab2, aw3, ab3,
                                                 eow, eob, eaw, eab, riw, rib, miw, mib,
                                                 out, ws);
  k356_attn<<<dim3(888), dim3(256), 0, stream>>>(ws);
  k7_epilogue<<<dim3(1104), dim3(128), 0, stream>>>(mow, mob, roww, robb, qw, qb, ws);
  k8_final<<<dim3(3), dim3(256), 0, stream>>>(ws, out);
}